// Round 1
// baseline (5005.967 us; speedup 1.0000x reference)
//
#include <hip/hip_runtime.h>
#include <hip/hip_bf16.h>
#include <cstdint>

#define IN_CH 512
#define HC    512   // HEADS*CH
#define HEADS 8

// ---------------- fp32 GEMM: C[M,N] = A[M,K] @ B[K,N], 64x64 tile, BK=16 ----
__global__ __launch_bounds__(256) void gemm_fp32(
    const float* __restrict__ A, const float* __restrict__ B, float* __restrict__ C,
    int M, int N, int K) {
  __shared__ float As[16][68];   // [k][row], padded
  __shared__ float Bs[16][68];   // [k][col], padded (row stride 272B = 16B-aligned)
  const int tid  = threadIdx.x;
  const int row0 = blockIdx.y * 64;
  const int col0 = blockIdx.x * 64;
  const int tr = tid >> 4;    // 0..15
  const int tc = tid & 15;    // 0..15
  float acc[4][4] = {};
  for (int k0 = 0; k0 < K; k0 += 16) {
    {
      const int r  = tid >> 2;          // 0..63
      const int kk = (tid & 3) << 2;    // 0,4,8,12
      const int gr = row0 + r;
      float4 v = make_float4(0.f, 0.f, 0.f, 0.f);
      if (gr < M) v = *(const float4*)(A + (size_t)gr * K + k0 + kk);
      As[kk + 0][r] = v.x; As[kk + 1][r] = v.y;
      As[kk + 2][r] = v.z; As[kk + 3][r] = v.w;
    }
    {
      const int kk = tid >> 4;          // 0..15
      const int cc = (tid & 15) << 2;   // 0..60
      float4 v = *(const float4*)(B + (size_t)(k0 + kk) * N + col0 + cc);
      *(float4*)&Bs[kk][cc] = v;
    }
    __syncthreads();
    #pragma unroll
    for (int kk = 0; kk < 16; ++kk) {
      float a[4], b[4];
      #pragma unroll
      for (int i = 0; i < 4; ++i) a[i] = As[kk][tr * 4 + i];
      #pragma unroll
      for (int j = 0; j < 4; ++j) b[j] = Bs[kk][tc * 4 + j];
      #pragma unroll
      for (int i = 0; i < 4; ++i)
        #pragma unroll
        for (int j = 0; j < 4; ++j)
          acc[i][j] += a[i] * b[j];
    }
    __syncthreads();
  }
  #pragma unroll
  for (int i = 0; i < 4; ++i) {
    const int gr = row0 + tr * 4 + i;
    if (gr < M) {
      #pragma unroll
      for (int j = 0; j < 4; ++j)
        C[(size_t)gr * N + col0 + tc * 4 + j] = acc[i][j];
    }
  }
}

// ------------- per-edge attention logits -> exp + denom atomics -------------
// 1 wave per edge; lane covers 8 consecutive channels (all inside head lane>>3)
__global__ void edge_alpha(const float* __restrict__ xl, const float* __restrict__ xr,
                           const int* __restrict__ ei, const float* __restrict__ att,
                           float* __restrict__ expalpha, float* __restrict__ denom,
                           int E) {
  const int wave = blockIdx.x * (blockDim.x >> 6) + (threadIdx.x >> 6);
  const int lane = threadIdx.x & 63;
  if (wave >= E) return;
  const int src = ei[wave];
  const int dst = ei[E + wave];
  const float4* pl = (const float4*)(xl + (size_t)src * HC + lane * 8);
  const float4* pr = (const float4*)(xr + (size_t)dst * HC + lane * 8);
  const float4* pa = (const float4*)(att + lane * 8);
  float4 a0 = pl[0], a1 = pl[1];
  float4 b0 = pr[0], b1 = pr[1];
  float4 t0 = pa[0], t1 = pa[1];
  auto lrelu = [](float v) { return v > 0.f ? v : 0.2f * v; };
  float s = 0.f;
  s += lrelu(a0.x + b0.x) * t0.x;
  s += lrelu(a0.y + b0.y) * t0.y;
  s += lrelu(a0.z + b0.z) * t0.z;
  s += lrelu(a0.w + b0.w) * t0.w;
  s += lrelu(a1.x + b1.x) * t1.x;
  s += lrelu(a1.y + b1.y) * t1.y;
  s += lrelu(a1.z + b1.z) * t1.z;
  s += lrelu(a1.w + b1.w) * t1.w;
  // reduce within the 8-lane head group
  s += __shfl_down(s, 4, 8);
  s += __shfl_down(s, 2, 8);
  s += __shfl_down(s, 1, 8);
  if ((lane & 7) == 0) {
    const int h = lane >> 3;
    const float ea = __expf(s);
    expalpha[(size_t)wave * HEADS + h] = ea;
    atomicAdd(&denom[(size_t)dst * HEADS + h], ea);
  }
}

// ------------- aggregation: agg[dst] += (ea/den) * xl[src] ------------------
__global__ void edge_agg(const float* __restrict__ xl, const int* __restrict__ ei,
                         const float* __restrict__ expalpha, const float* __restrict__ denom,
                         float* __restrict__ agg, int E) {
  const int wave = blockIdx.x * (blockDim.x >> 6) + (threadIdx.x >> 6);
  const int lane = threadIdx.x & 63;
  if (wave >= E) return;
  const int src = ei[wave];
  const int dst = ei[E + wave];
  const int h = lane >> 3;
  const float w = expalpha[(size_t)wave * HEADS + h] /
                  (denom[(size_t)dst * HEADS + h] + 1e-16f);
  const float4* pl = (const float4*)(xl + (size_t)src * HC + lane * 8);
  float4 a0 = pl[0], a1 = pl[1];
  float* pd = agg + (size_t)dst * HC + lane * 8;
  atomicAdd(pd + 0, w * a0.x);
  atomicAdd(pd + 1, w * a0.y);
  atomicAdd(pd + 2, w * a0.z);
  atomicAdd(pd + 3, w * a0.w);
  atomicAdd(pd + 4, w * a1.x);
  atomicAdd(pd + 5, w * a1.y);
  atomicAdd(pd + 6, w * a1.z);
  atomicAdd(pd + 7, w * a1.w);
}

// ------------- BatchNorm stats: per-channel sum / sumsq ---------------------
__global__ void bn_stats(const float* __restrict__ agg, float* __restrict__ gsum,
                         float* __restrict__ gsq, int Nn) {
  const int t = threadIdx.x;  // 256
  const int rows_per_block = (Nn + gridDim.x - 1) / gridDim.x;
  const int r0 = blockIdx.x * rows_per_block;
  const int r1 = min(Nn, r0 + rows_per_block);
  float s0 = 0.f, s1 = 0.f, q0 = 0.f, q1 = 0.f;
  for (int r = r0; r < r1; ++r) {
    const float v0 = agg[(size_t)r * HC + t];
    const float v1 = agg[(size_t)r * HC + t + 256];
    s0 += v0; q0 += v0 * v0;
    s1 += v1; q1 += v1 * v1;
  }
  atomicAdd(&gsum[t], s0);
  atomicAdd(&gsum[t + 256], s1);
  atomicAdd(&gsq[t], q0);
  atomicAdd(&gsq[t + 256], q1);
}

__global__ void bn_final(const float* __restrict__ gsum, const float* __restrict__ gsq,
                         float* __restrict__ mu, float* __restrict__ rs, float invN) {
  const int c = threadIdx.x;  // 512
  const float m = gsum[c] * invN;
  const float v = gsq[c] * invN - m * m;
  mu[c] = m;
  rs[c] = rsqrtf(v + 1e-5f);
}

// ------------- BN apply + ReLU (bias cancels in train-mode BN) --------------
__global__ void bn_apply(const float* __restrict__ agg, const float* __restrict__ mu,
                         const float* __restrict__ rs, const float* __restrict__ gamma,
                         const float* __restrict__ beta, float* __restrict__ y, int total4) {
  const int i = blockIdx.x * blockDim.x + threadIdx.x;
  if (i >= total4) return;
  const int base = i << 2;
  const int c = base & (HC - 1);
  float4 v = *(const float4*)(agg + base);
  float4 o;
  o.x = fmaxf(0.f, (v.x - mu[c + 0]) * rs[c + 0] * gamma[c + 0] + beta[c + 0]);
  o.y = fmaxf(0.f, (v.y - mu[c + 1]) * rs[c + 1] * gamma[c + 1] + beta[c + 1]);
  o.z = fmaxf(0.f, (v.z - mu[c + 2]) * rs[c + 2] * gamma[c + 2] + beta[c + 2]);
  o.w = fmaxf(0.f, (v.w - mu[c + 3]) * rs[c + 3] * gamma[c + 3] + beta[c + 3]);
  *(float4*)(y + base) = o;
}

// ------------- link scoring: out[e] = dot(y[s], y[t]) -----------------------
__global__ void score(const float* __restrict__ y, const int* __restrict__ eli,
                      float* __restrict__ out, int EL) {
  const int wave = blockIdx.x * (blockDim.x >> 6) + (threadIdx.x >> 6);
  const int lane = threadIdx.x & 63;
  if (wave >= EL) return;
  const int a = eli[wave];
  const int b = eli[EL + wave];
  const float4* pa = (const float4*)(y + (size_t)a * HC + lane * 8);
  const float4* pb = (const float4*)(y + (size_t)b * HC + lane * 8);
  float4 u0 = pa[0], u1 = pa[1];
  float4 v0 = pb[0], v1 = pb[1];
  float s = u0.x * v0.x + u0.y * v0.y + u0.z * v0.z + u0.w * v0.w +
            u1.x * v1.x + u1.y * v1.y + u1.z * v1.z + u1.w * v1.w;
  #pragma unroll
  for (int off = 32; off > 0; off >>= 1) s += __shfl_down(s, off, 64);
  if (lane == 0) out[wave] = s;
}

extern "C" void kernel_launch(void* const* d_in, const int* in_sizes, int n_in,
                              void* d_out, int out_size, void* d_ws, size_t ws_size,
                              hipStream_t stream) {
  const float* x     = (const float*)d_in[0];
  const int*   ei    = (const int*)d_in[1];
  const int*   eli   = (const int*)d_in[2];
  const float* W_l   = (const float*)d_in[3];
  const float* W_r   = (const float*)d_in[4];
  const float* att   = (const float*)d_in[5];
  // d_in[6] = bias: cancels exactly inside train-mode BatchNorm -> unused.
  const float* gamma = (const float*)d_in[7];
  const float* beta  = (const float*)d_in[8];
  float* out = (float*)d_out;

  const int Nn = in_sizes[0] / IN_CH;  // 20000
  const int E  = in_sizes[1] / 2;      // 320000
  const int EL = in_sizes[2] / 2;      // 100000

  float* ws       = (float*)d_ws;
  float* xl       = ws;                                  // Nn*HC
  float* xr       = xl + (size_t)Nn * HC;                // Nn*HC (reused as agg)
  float* expalpha = xr + (size_t)Nn * HC;                // E*HEADS
  float* denom    = expalpha + (size_t)E * HEADS;        // Nn*HEADS
  float* gsum     = denom + (size_t)Nn * HEADS;          // HC
  float* gsq      = gsum + HC;                           // HC
  float* mu       = gsq + HC;                            // HC
  float* rs       = mu + HC;                             // HC
  float* agg      = xr;   // xr dead after edge_alpha
  float* y        = xl;   // xl dead after edge_agg

  // 1) xl = x @ W_l ; xr = x @ W_r
  dim3 ggrid(HC / 64, (Nn + 63) / 64);
  gemm_fp32<<<ggrid, 256, 0, stream>>>(x, W_l, xl, Nn, HC, IN_CH);
  gemm_fp32<<<ggrid, 256, 0, stream>>>(x, W_r, xr, Nn, HC, IN_CH);

  // 2) per-edge logits -> exp, softmax denominators
  hipMemsetAsync(denom, 0, (size_t)Nn * HEADS * sizeof(float), stream);
  edge_alpha<<<(E + 3) / 4, 256, 0, stream>>>(xl, xr, ei, att, expalpha, denom, E);

  // 3) weighted scatter-add aggregation
  hipMemsetAsync(agg, 0, (size_t)Nn * HC * sizeof(float), stream);
  edge_agg<<<(E + 3) / 4, 256, 0, stream>>>(xl, ei, expalpha, denom, agg, E);

  // 4) BatchNorm (train-mode batch stats) + ReLU
  hipMemsetAsync(gsum, 0, 2 * HC * sizeof(float), stream);
  bn_stats<<<200, 256, 0, stream>>>(agg, gsum, gsq, Nn);
  bn_final<<<1, HC, 0, stream>>>(gsum, gsq, mu, rs, 1.0f / (float)Nn);
  bn_apply<<<(Nn * HC / 4 + 255) / 256, 256, 0, stream>>>(agg, mu, rs, gamma, beta, y,
                                                          Nn * HC / 4);

  // 5) link scoring
  score<<<(EL + 3) / 4, 256, 0, stream>>>(y, eli, out, EL);
}

// Round 2
// 608.167 us; speedup vs baseline: 8.2312x; 8.2312x over previous
//
#include <hip/hip_runtime.h>
#include <hip/hip_bf16.h>
#include <cstdint>

#define IN_CH 512
#define HC    512   // HEADS*CH
#define HEADS 8

// ---------------- fp32 GEMM: C[M,N] = A[M,K] @ B[K,N], 64x64 tile, BK=16 ----
__global__ __launch_bounds__(256) void gemm_fp32(
    const float* __restrict__ A, const float* __restrict__ B, float* __restrict__ C,
    int M, int N, int K) {
  __shared__ float As[16][68];
  __shared__ float Bs[16][68];
  const int tid  = threadIdx.x;
  const int row0 = blockIdx.y * 64;
  const int col0 = blockIdx.x * 64;
  const int tr = tid >> 4;
  const int tc = tid & 15;
  float acc[4][4] = {};
  for (int k0 = 0; k0 < K; k0 += 16) {
    {
      const int r  = tid >> 2;
      const int kk = (tid & 3) << 2;
      const int gr = row0 + r;
      float4 v = make_float4(0.f, 0.f, 0.f, 0.f);
      if (gr < M) v = *(const float4*)(A + (size_t)gr * K + k0 + kk);
      As[kk + 0][r] = v.x; As[kk + 1][r] = v.y;
      As[kk + 2][r] = v.z; As[kk + 3][r] = v.w;
    }
    {
      const int kk = tid >> 4;
      const int cc = (tid & 15) << 2;
      float4 v = *(const float4*)(B + (size_t)(k0 + kk) * N + col0 + cc);
      *(float4*)&Bs[kk][cc] = v;
    }
    __syncthreads();
    #pragma unroll
    for (int kk = 0; kk < 16; ++kk) {
      float a[4], b[4];
      #pragma unroll
      for (int i = 0; i < 4; ++i) a[i] = As[kk][tr * 4 + i];
      #pragma unroll
      for (int j = 0; j < 4; ++j) b[j] = Bs[kk][tc * 4 + j];
      #pragma unroll
      for (int i = 0; i < 4; ++i)
        #pragma unroll
        for (int j = 0; j < 4; ++j)
          acc[i][j] += a[i] * b[j];
    }
    __syncthreads();
  }
  #pragma unroll
  for (int i = 0; i < 4; ++i) {
    const int gr = row0 + tr * 4 + i;
    if (gr < M) {
      #pragma unroll
      for (int j = 0; j < 4; ++j)
        C[(size_t)gr * N + col0 + tc * 4 + j] = acc[i][j];
    }
  }
}

// ---------------- CSR build: histogram -> scan -> fill ----------------------
__global__ void hist_dst(const int* __restrict__ ei, int* __restrict__ counts, int E) {
  const int e = blockIdx.x * blockDim.x + threadIdx.x;
  if (e < E) atomicAdd(&counts[ei[E + e]], 1);
}

__global__ void scan1(const int* __restrict__ counts, int* __restrict__ offsets,
                      int* __restrict__ bsums, int Nn) {
  __shared__ int tmp[256];
  const int t = threadIdx.x;
  const int i = blockIdx.x * 256 + t;
  const int v = (i < Nn) ? counts[i] : 0;
  tmp[t] = v;
  __syncthreads();
  for (int d = 1; d < 256; d <<= 1) {
    int add = (t >= d) ? tmp[t - d] : 0;
    __syncthreads();
    tmp[t] += add;
    __syncthreads();
  }
  if (i < Nn) offsets[i] = tmp[t] - v;  // exclusive
  if (t == 255) bsums[blockIdx.x] = tmp[255];
}

__global__ void scan2(int* __restrict__ bsums, int nb) {
  __shared__ int tmp[256];
  const int t = threadIdx.x;
  if (t < nb) tmp[t] = bsums[t];
  __syncthreads();
  if (t == 0) {
    int run = 0;
    for (int b = 0; b < nb; ++b) { int c = tmp[b]; tmp[b] = run; run += c; }
  }
  __syncthreads();
  if (t < nb) bsums[t] = tmp[t];
}

__global__ void scan3(int* __restrict__ offsets, const int* __restrict__ bsums,
                      int* __restrict__ cursor, int Nn) {
  const int i = blockIdx.x * blockDim.x + threadIdx.x;
  if (i < Nn) {
    const int o = offsets[i] + bsums[i >> 8];
    offsets[i] = o;
    cursor[i] = o;
  }
}

__global__ void csr_fill(const int* __restrict__ ei, int* __restrict__ cursor,
                         int* __restrict__ csr_src, int E) {
  const int e = blockIdx.x * blockDim.x + threadIdx.x;
  if (e < E) {
    const int pos = atomicAdd(&cursor[ei[E + e]], 1);
    csr_src[pos] = ei[e];  // store SOURCE NODE id directly (edge id not needed)
  }
}

// ------- fused GATv2: logits + softmax + weighted aggregation, 1 wave/node --
// agg may alias xr: each wave reads only xr[node] (into regs, up front) and
// writes only agg[node] (at the end) -> row-local, safe.
__global__ __launch_bounds__(256) void gatv2_agg(
    const float* __restrict__ xl, const float* xr, const float* __restrict__ att,
    const int* __restrict__ offsets, const int* __restrict__ counts,
    const int* __restrict__ csr_src, float* agg, int Nn) {
  const int node = blockIdx.x * 4 + (threadIdx.x >> 6);
  const int lane = threadIdx.x & 63;
  if (node >= Nn) return;
  const int start = offsets[node];
  const int deg   = counts[node];
  const float4* pr = (const float4*)(xr + (size_t)node * HC + lane * 8);
  const float4 r0 = pr[0], r1 = pr[1];
  const float4* pa = (const float4*)(att + lane * 8);
  const float4 t0 = pa[0], t1 = pa[1];
  float acc[8] = {};
  float densum = 0.f;
  auto lrelu = [](float v) { return v > 0.f ? v : 0.2f * v; };
  for (int i = 0; i < deg; ++i) {
    const int src = csr_src[start + i];
    const float4* pl = (const float4*)(xl + (size_t)src * HC + lane * 8);
    const float4 a0 = pl[0], a1 = pl[1];
    float s = lrelu(a0.x + r0.x) * t0.x + lrelu(a0.y + r0.y) * t0.y +
              lrelu(a0.z + r0.z) * t0.z + lrelu(a0.w + r0.w) * t0.w +
              lrelu(a1.x + r1.x) * t1.x + lrelu(a1.y + r1.y) * t1.y +
              lrelu(a1.z + r1.z) * t1.z + lrelu(a1.w + r1.w) * t1.w;
    // reduce across the 8 lanes of this head; all 8 lanes end with the sum
    s += __shfl_xor(s, 1, 8);
    s += __shfl_xor(s, 2, 8);
    s += __shfl_xor(s, 4, 8);
    const float ea = __expf(s);
    densum += ea;
    acc[0] += ea * a0.x; acc[1] += ea * a0.y; acc[2] += ea * a0.z; acc[3] += ea * a0.w;
    acc[4] += ea * a1.x; acc[5] += ea * a1.y; acc[6] += ea * a1.z; acc[7] += ea * a1.w;
  }
  const float inv = 1.0f / (densum + 1e-16f);
  float* pd = agg + (size_t)node * HC + lane * 8;
  *(float4*)(pd + 0) = make_float4(acc[0] * inv, acc[1] * inv, acc[2] * inv, acc[3] * inv);
  *(float4*)(pd + 4) = make_float4(acc[4] * inv, acc[5] * inv, acc[6] * inv, acc[7] * inv);
}

// ------------- BatchNorm stats: per-channel sum / sumsq ---------------------
__global__ void bn_stats(const float* __restrict__ agg, float* __restrict__ gsum,
                         float* __restrict__ gsq, int Nn) {
  const int t = threadIdx.x;  // 256
  const int rows_per_block = (Nn + gridDim.x - 1) / gridDim.x;
  const int r0 = blockIdx.x * rows_per_block;
  const int r1 = min(Nn, r0 + rows_per_block);
  float s0 = 0.f, s1 = 0.f, q0 = 0.f, q1 = 0.f;
  for (int r = r0; r < r1; ++r) {
    const float v0 = agg[(size_t)r * HC + t];
    const float v1 = agg[(size_t)r * HC + t + 256];
    s0 += v0; q0 += v0 * v0;
    s1 += v1; q1 += v1 * v1;
  }
  atomicAdd(&gsum[t], s0);
  atomicAdd(&gsum[t + 256], s1);
  atomicAdd(&gsq[t], q0);
  atomicAdd(&gsq[t + 256], q1);
}

__global__ void bn_final(const float* __restrict__ gsum, const float* __restrict__ gsq,
                         float* __restrict__ mu, float* __restrict__ rs, float invN) {
  const int c = threadIdx.x;  // 512
  const float m = gsum[c] * invN;
  const float v = gsq[c] * invN - m * m;
  mu[c] = m;
  rs[c] = rsqrtf(v + 1e-5f);
}

// ------------- BN apply + ReLU (bias cancels in train-mode BN) --------------
__global__ void bn_apply(const float* __restrict__ agg, const float* __restrict__ mu,
                         const float* __restrict__ rs, const float* __restrict__ gamma,
                         const float* __restrict__ beta, float* __restrict__ y, int total4) {
  const int i = blockIdx.x * blockDim.x + threadIdx.x;
  if (i >= total4) return;
  const int base = i << 2;
  const int c = base & (HC - 1);
  float4 v = *(const float4*)(agg + base);
  float4 o;
  o.x = fmaxf(0.f, (v.x - mu[c + 0]) * rs[c + 0] * gamma[c + 0] + beta[c + 0]);
  o.y = fmaxf(0.f, (v.y - mu[c + 1]) * rs[c + 1] * gamma[c + 1] + beta[c + 1]);
  o.z = fmaxf(0.f, (v.z - mu[c + 2]) * rs[c + 2] * gamma[c + 2] + beta[c + 2]);
  o.w = fmaxf(0.f, (v.w - mu[c + 3]) * rs[c + 3] * gamma[c + 3] + beta[c + 3]);
  *(float4*)(y + base) = o;
}

// ------------- link scoring: out[e] = dot(y[s], y[t]) -----------------------
__global__ void score(const float* __restrict__ y, const int* __restrict__ eli,
                      float* __restrict__ out, int EL) {
  const int wave = blockIdx.x * (blockDim.x >> 6) + (threadIdx.x >> 6);
  const int lane = threadIdx.x & 63;
  if (wave >= EL) return;
  const int a = eli[wave];
  const int b = eli[EL + wave];
  const float4* pa = (const float4*)(y + (size_t)a * HC + lane * 8);
  const float4* pb = (const float4*)(y + (size_t)b * HC + lane * 8);
  float4 u0 = pa[0], u1 = pa[1];
  float4 v0 = pb[0], v1 = pb[1];
  float s = u0.x * v0.x + u0.y * v0.y + u0.z * v0.z + u0.w * v0.w +
            u1.x * v1.x + u1.y * v1.y + u1.z * v1.z + u1.w * v1.w;
  #pragma unroll
  for (int off = 32; off > 0; off >>= 1) s += __shfl_down(s, off, 64);
  if (lane == 0) out[wave] = s;
}

extern "C" void kernel_launch(void* const* d_in, const int* in_sizes, int n_in,
                              void* d_out, int out_size, void* d_ws, size_t ws_size,
                              hipStream_t stream) {
  const float* x     = (const float*)d_in[0];
  const int*   ei    = (const int*)d_in[1];
  const int*   eli   = (const int*)d_in[2];
  const float* W_l   = (const float*)d_in[3];
  const float* W_r   = (const float*)d_in[4];
  const float* att   = (const float*)d_in[5];
  // d_in[6] = bias: cancels exactly inside train-mode BatchNorm -> unused.
  const float* gamma = (const float*)d_in[7];
  const float* beta  = (const float*)d_in[8];
  float* out = (float*)d_out;

  const int Nn = in_sizes[0] / IN_CH;  // 20000
  const int E  = in_sizes[1] / 2;      // 320000
  const int EL = in_sizes[2] / 2;      // 100000

  float* ws = (float*)d_ws;
  float* xl = ws;                          // Nn*HC   (reused as y)
  float* xr = xl + (size_t)Nn * HC;        // Nn*HC   (reused as agg, row-local)
  int* counts  = (int*)(xr + (size_t)Nn * HC);  // Nn
  int* offsets = counts + Nn;                   // Nn
  int* cursor  = offsets + Nn;                  // Nn
  int* bsums   = cursor + Nn;                   // 256
  int* csr_src = bsums + 256;                   // E
  float* gsum  = (float*)(csr_src + E);         // HC
  float* gsq   = gsum + HC;                     // HC
  float* mu    = gsq + HC;                      // HC
  float* rs    = mu + HC;                       // HC
  float* agg   = xr;
  float* y     = xl;

  const int nb = (Nn + 255) / 256;  // scan blocks (79)

  // 1) xl = x @ W_l ; xr = x @ W_r
  dim3 ggrid(HC / 64, (Nn + 63) / 64);
  gemm_fp32<<<ggrid, 256, 0, stream>>>(x, W_l, xl, Nn, HC, IN_CH);
  gemm_fp32<<<ggrid, 256, 0, stream>>>(x, W_r, xr, Nn, HC, IN_CH);

  // 2) CSR by destination
  hipMemsetAsync(counts, 0, Nn * sizeof(int), stream);
  hist_dst<<<(E + 255) / 256, 256, 0, stream>>>(ei, counts, E);
  scan1<<<nb, 256, 0, stream>>>(counts, offsets, bsums, Nn);
  scan2<<<1, 256, 0, stream>>>(bsums, nb);
  scan3<<<nb, 256, 0, stream>>>(offsets, bsums, cursor, Nn);
  csr_fill<<<(E + 255) / 256, 256, 0, stream>>>(ei, cursor, csr_src, E);

  // 3) fused attention + softmax + aggregation (no atomics, 1 wave/node)
  gatv2_agg<<<(Nn + 3) / 4, 256, 0, stream>>>(xl, xr, att, offsets, counts,
                                              csr_src, agg, Nn);

  // 4) BatchNorm (train-mode batch stats) + ReLU
  hipMemsetAsync(gsum, 0, 2 * HC * sizeof(float), stream);
  bn_stats<<<200, 256, 0, stream>>>(agg, gsum, gsq, Nn);
  bn_final<<<1, HC, 0, stream>>>(gsum, gsq, mu, rs, 1.0f / (float)Nn);
  bn_apply<<<(Nn * HC / 4 + 255) / 256, 256, 0, stream>>>(agg, mu, rs, gamma, beta, y,
                                                          Nn * HC / 4);

  // 5) link scoring
  score<<<(EL + 3) / 4, 256, 0, stream>>>(y, eli, out, EL);
}

// Round 3
// 390.189 us; speedup vs baseline: 12.8296x; 1.5586x over previous
//
#include <hip/hip_runtime.h>
#include <hip/hip_bf16.h>
#include <cstdint>

#define IN_CH 512
#define HC    512   // HEADS*CH
#define HEADS 8
#define NPACK 1024  // W_l | W_r packed

typedef __attribute__((ext_vector_type(8))) short bf16x8;
typedef __attribute__((ext_vector_type(4))) float f32x4;
typedef const __attribute__((address_space(1))) uint8_t* gaddr_t;
typedef __attribute__((address_space(3))) uint8_t* laddr_t;

__device__ inline ushort f2bf(float f) {  // round-to-nearest-even
  uint32_t u = __float_as_uint(f);
  return (ushort)((u + 0x7fffu + ((u >> 16) & 1u)) >> 16);
}

// ---- cast x (fp32) -> bf16, vectorized -------------------------------------
__global__ void cast_x(const float* __restrict__ x, ushort* __restrict__ xb, int n4) {
  const int i = blockIdx.x * blockDim.x + threadIdx.x;
  if (i >= n4) return;
  const float4 v = ((const float4*)x)[i];
  ushort4 o;
  o.x = f2bf(v.x); o.y = f2bf(v.y); o.z = f2bf(v.z); o.w = f2bf(v.w);
  ((ushort4*)xb)[i] = o;
}

// ---- pack [W_l | W_r] transposed -> Bt[n][k] bf16 --------------------------
__global__ void pack_w(const float* __restrict__ Wl, const float* __restrict__ Wr,
                       ushort* __restrict__ bt) {
  const int i = blockIdx.x * blockDim.x + threadIdx.x;  // n*512 + k
  if (i >= NPACK * IN_CH) return;
  const int n = i >> 9, k = i & 511;
  const float v = (n < HC) ? Wl[(size_t)k * HC + n] : Wr[(size_t)k * HC + (n - HC)];
  bt[i] = f2bf(v);
}

// ---- bf16 MFMA GEMM: C[M,1024] = xb[M,512] @ Bt^T, split into xl|xr --------
// 128x128 tile, BK=32, global_load_lds width=16, 16x16x32 bf16 MFMA.
__global__ __launch_bounds__(256) void gemm_mfma(
    const ushort* __restrict__ xb, const ushort* __restrict__ bt,
    float* __restrict__ xl, float* __restrict__ xr, int M) {
  __shared__ __align__(16) ushort As[128 * 32];  // [row][k], stride 32
  __shared__ __align__(16) ushort Bs[128 * 32];  // [col][k], stride 32
  const int wave = threadIdx.x >> 6, lane = threadIdx.x & 63;
  const int row0 = blockIdx.y * 128, col0 = blockIdx.x * 128;
  const int quad = lane >> 4, m16 = lane & 15;
  const int wrow = (wave >> 1) * 64, wcol = (wave & 1) * 64;
  const int srow = lane >> 2;        // staging: row within 16-row chunk
  const int scol = (lane & 3) * 8;   // staging: bf16 element offset in row
  const f32x4 zero = {0.f, 0.f, 0.f, 0.f};
  f32x4 acc[4][4];
  #pragma unroll
  for (int i = 0; i < 4; ++i)
    #pragma unroll
    for (int j = 0; j < 4; ++j) acc[i][j] = zero;

  for (int k0 = 0; k0 < IN_CH; k0 += 32) {
    #pragma unroll
    for (int c = 0; c < 2; ++c) {
      const int chunk = wave * 2 + c;  // 0..7, 16 rows each
      const ushort* ga = xb + (size_t)(row0 + chunk * 16 + srow) * IN_CH + k0 + scol;
      __builtin_amdgcn_global_load_lds((gaddr_t)ga, (laddr_t)(As + chunk * 512), 16, 0, 0);
      const ushort* gb = bt + (size_t)(col0 + chunk * 16 + srow) * IN_CH + k0 + scol;
      __builtin_amdgcn_global_load_lds((gaddr_t)gb, (laddr_t)(Bs + chunk * 512), 16, 0, 0);
    }
    __syncthreads();
    bf16x8 af[4], bfr[4];
    #pragma unroll
    for (int i = 0; i < 4; ++i)
      af[i] = *(const bf16x8*)(As + (wrow + i * 16 + m16) * 32 + quad * 8);
    #pragma unroll
    for (int j = 0; j < 4; ++j)
      bfr[j] = *(const bf16x8*)(Bs + (wcol + j * 16 + m16) * 32 + quad * 8);
    #pragma unroll
    for (int i = 0; i < 4; ++i)
      #pragma unroll
      for (int j = 0; j < 4; ++j)
        acc[i][j] = __builtin_amdgcn_mfma_f32_16x16x32_bf16(af[i], bfr[j], acc[i][j], 0, 0, 0);
    __syncthreads();
  }
  // epilogue: C/D layout col=lane&15, row=quad*4+reg (m89/m91-verified)
  #pragma unroll
  for (int i = 0; i < 4; ++i) {
    const int r = row0 + wrow + i * 16 + quad * 4;
    #pragma unroll
    for (int j = 0; j < 4; ++j) {
      const int cg = col0 + wcol + j * 16 + m16;
      #pragma unroll
      for (int t = 0; t < 4; ++t) {
        const int rr = r + t;
        if (rr < M) {
          if (cg < HC) xl[(size_t)rr * HC + cg] = acc[i][j][t];
          else         xr[(size_t)rr * HC + (cg - HC)] = acc[i][j][t];
        }
      }
    }
  }
}

// ---------------- CSR build: histogram -> scan -> fill ----------------------
__global__ void hist_dst(const int* __restrict__ ei, int* __restrict__ counts, int E) {
  const int e = blockIdx.x * blockDim.x + threadIdx.x;
  if (e < E) atomicAdd(&counts[ei[E + e]], 1);
}

__global__ void scan1(const int* __restrict__ counts, int* __restrict__ offsets,
                      int* __restrict__ bsums, int Nn) {
  __shared__ int tmp[256];
  const int t = threadIdx.x;
  const int i = blockIdx.x * 256 + t;
  const int v = (i < Nn) ? counts[i] : 0;
  tmp[t] = v;
  __syncthreads();
  for (int d = 1; d < 256; d <<= 1) {
    int add = (t >= d) ? tmp[t - d] : 0;
    __syncthreads();
    tmp[t] += add;
    __syncthreads();
  }
  if (i < Nn) offsets[i] = tmp[t] - v;  // exclusive
  if (t == 255) bsums[blockIdx.x] = tmp[255];
}

__global__ void scan2(int* __restrict__ bsums, int nb) {
  __shared__ int tmp[256];
  const int t = threadIdx.x;
  if (t < nb) tmp[t] = bsums[t];
  __syncthreads();
  if (t == 0) {
    int run = 0;
    for (int b = 0; b < nb; ++b) { int c = tmp[b]; tmp[b] = run; run += c; }
  }
  __syncthreads();
  if (t < nb) bsums[t] = tmp[t];
}

__global__ void scan3(int* __restrict__ offsets, const int* __restrict__ bsums,
                      int* __restrict__ cursor, int Nn) {
  const int i = blockIdx.x * blockDim.x + threadIdx.x;
  if (i < Nn) {
    const int o = offsets[i] + bsums[i >> 8];
    offsets[i] = o;
    cursor[i] = o;
  }
}

__global__ void csr_fill(const int* __restrict__ ei, int* __restrict__ cursor,
                         int* __restrict__ csr_src, int E) {
  const int e = blockIdx.x * blockDim.x + threadIdx.x;
  if (e < E) {
    const int pos = atomicAdd(&cursor[ei[E + e]], 1);
    csr_src[pos] = ei[e];
  }
}

// ------- fused GATv2: logits + softmax + weighted aggregation, 1 wave/node --
__global__ __launch_bounds__(256) void gatv2_agg(
    const float* __restrict__ xl, const float* xr, const float* __restrict__ att,
    const int* __restrict__ offsets, const int* __restrict__ counts,
    const int* __restrict__ csr_src, float* agg, int Nn) {
  const int node = blockIdx.x * 4 + (threadIdx.x >> 6);
  const int lane = threadIdx.x & 63;
  if (node >= Nn) return;
  const int start = offsets[node];
  const int deg   = counts[node];
  const float4* pr = (const float4*)(xr + (size_t)node * HC + lane * 8);
  const float4 r0 = pr[0], r1 = pr[1];
  const float4* pa = (const float4*)(att + lane * 8);
  const float4 t0 = pa[0], t1 = pa[1];
  float acc[8] = {};
  float densum = 0.f;
  auto lrelu = [](float v) { return v > 0.f ? v : 0.2f * v; };
  for (int i = 0; i < deg; ++i) {
    const int src = csr_src[start + i];
    const float4* pl = (const float4*)(xl + (size_t)src * HC + lane * 8);
    const float4 a0 = pl[0], a1 = pl[1];
    float s = lrelu(a0.x + r0.x) * t0.x + lrelu(a0.y + r0.y) * t0.y +
              lrelu(a0.z + r0.z) * t0.z + lrelu(a0.w + r0.w) * t0.w +
              lrelu(a1.x + r1.x) * t1.x + lrelu(a1.y + r1.y) * t1.y +
              lrelu(a1.z + r1.z) * t1.z + lrelu(a1.w + r1.w) * t1.w;
    s += __shfl_xor(s, 1, 8);
    s += __shfl_xor(s, 2, 8);
    s += __shfl_xor(s, 4, 8);
    const float ea = __expf(s);
    densum += ea;
    acc[0] += ea * a0.x; acc[1] += ea * a0.y; acc[2] += ea * a0.z; acc[3] += ea * a0.w;
    acc[4] += ea * a1.x; acc[5] += ea * a1.y; acc[6] += ea * a1.z; acc[7] += ea * a1.w;
  }
  const float inv = 1.0f / (densum + 1e-16f);
  float* pd = agg + (size_t)node * HC + lane * 8;
  *(float4*)(pd + 0) = make_float4(acc[0] * inv, acc[1] * inv, acc[2] * inv, acc[3] * inv);
  *(float4*)(pd + 4) = make_float4(acc[4] * inv, acc[5] * inv, acc[6] * inv, acc[7] * inv);
}

// ------------- BatchNorm stats: per-channel sum / sumsq ---------------------
__global__ void bn_stats(const float* __restrict__ agg, float* __restrict__ gsum,
                         float* __restrict__ gsq, int Nn) {
  const int t = threadIdx.x;  // 256
  const int rows_per_block = (Nn + gridDim.x - 1) / gridDim.x;
  const int r0 = blockIdx.x * rows_per_block;
  const int r1 = min(Nn, r0 + rows_per_block);
  float s0 = 0.f, s1 = 0.f, q0 = 0.f, q1 = 0.f;
  for (int r = r0; r < r1; ++r) {
    const float v0 = agg[(size_t)r * HC + t];
    const float v1 = agg[(size_t)r * HC + t + 256];
    s0 += v0; q0 += v0 * v0;
    s1 += v1; q1 += v1 * v1;
  }
  atomicAdd(&gsum[t], s0);
  atomicAdd(&gsum[t + 256], s1);
  atomicAdd(&gsq[t], q0);
  atomicAdd(&gsq[t + 256], q1);
}

__global__ void bn_final(const float* __restrict__ gsum, const float* __restrict__ gsq,
                         float* __restrict__ mu, float* __restrict__ rs, float invN) {
  const int c = threadIdx.x;  // 512
  const float m = gsum[c] * invN;
  const float v = gsq[c] * invN - m * m;
  mu[c] = m;
  rs[c] = rsqrtf(v + 1e-5f);
}

// ------------- BN apply + ReLU (bias cancels in train-mode BN) --------------
__global__ void bn_apply(const float* __restrict__ agg, const float* __restrict__ mu,
                         const float* __restrict__ rs, const float* __restrict__ gamma,
                         const float* __restrict__ beta, float* __restrict__ y, int total4) {
  const int i = blockIdx.x * blockDim.x + threadIdx.x;
  if (i >= total4) return;
  const int base = i << 2;
  const int c = base & (HC - 1);
  float4 v = *(const float4*)(agg + base);
  float4 o;
  o.x = fmaxf(0.f, (v.x - mu[c + 0]) * rs[c + 0] * gamma[c + 0] + beta[c + 0]);
  o.y = fmaxf(0.f, (v.y - mu[c + 1]) * rs[c + 1] * gamma[c + 1] + beta[c + 1]);
  o.z = fmaxf(0.f, (v.z - mu[c + 2]) * rs[c + 2] * gamma[c + 2] + beta[c + 2]);
  o.w = fmaxf(0.f, (v.w - mu[c + 3]) * rs[c + 3] * gamma[c + 3] + beta[c + 3]);
  *(float4*)(y + base) = o;
}

// ------------- link scoring: out[e] = dot(y[s], y[t]) -----------------------
__global__ void score(const float* __restrict__ y, const int* __restrict__ eli,
                      float* __restrict__ out, int EL) {
  const int wave = blockIdx.x * (blockDim.x >> 6) + (threadIdx.x >> 6);
  const int lane = threadIdx.x & 63;
  if (wave >= EL) return;
  const int a = eli[wave];
  const int b = eli[EL + wave];
  const float4* pa = (const float4*)(y + (size_t)a * HC + lane * 8);
  const float4* pb = (const float4*)(y + (size_t)b * HC + lane * 8);
  float4 u0 = pa[0], u1 = pa[1];
  float4 v0 = pb[0], v1 = pb[1];
  float s = u0.x * v0.x + u0.y * v0.y + u0.z * v0.z + u0.w * v0.w +
            u1.x * v1.x + u1.y * v1.y + u1.z * v1.z + u1.w * v1.w;
  #pragma unroll
  for (int off = 32; off > 0; off >>= 1) s += __shfl_down(s, off, 64);
  if (lane == 0) out[wave] = s;
}

extern "C" void kernel_launch(void* const* d_in, const int* in_sizes, int n_in,
                              void* d_out, int out_size, void* d_ws, size_t ws_size,
                              hipStream_t stream) {
  const float* x     = (const float*)d_in[0];
  const int*   ei    = (const int*)d_in[1];
  const int*   eli   = (const int*)d_in[2];
  const float* W_l   = (const float*)d_in[3];
  const float* W_r   = (const float*)d_in[4];
  const float* att   = (const float*)d_in[5];
  // d_in[6] = bias: cancels exactly inside train-mode BatchNorm -> unused.
  const float* gamma = (const float*)d_in[7];
  const float* beta  = (const float*)d_in[8];
  float* out = (float*)d_out;

  const int Nn = in_sizes[0] / IN_CH;  // 20000
  const int E  = in_sizes[1] / 2;      // 320000
  const int EL = in_sizes[2] / 2;      // 100000

  float* ws = (float*)d_ws;
  float*  xl  = ws;                                   // Nn*HC (reused as y)
  float*  xr  = xl + (size_t)Nn * HC;                 // Nn*HC (reused as agg)
  ushort* xbf = (ushort*)(xr + (size_t)Nn * HC);      // Nn*IN_CH bf16
  ushort* btb = xbf + (size_t)Nn * IN_CH;             // NPACK*IN_CH bf16
  // CSR + BN scratch aliases INTO xbf region (xbf dead after gemm_mfma;
  // all aliased users are stream-ordered after it):
  int* counts  = (int*)xbf;              // Nn
  int* offsets = counts + Nn;            // Nn
  int* cursor  = offsets + Nn;           // Nn
  int* bsums   = cursor + Nn;            // 256
  int* csr_src = bsums + 256;            // E
  float* gsum  = (float*)(csr_src + E);  // HC
  float* gsq   = gsum + HC;              // HC
  float* mu    = gsq + HC;               // HC
  float* rs    = mu + HC;                // HC
  float* agg   = xr;
  float* y     = xl;

  const int nb = (Nn + 255) / 256;

  // 1) casts + packed-transposed weights, then one bf16 MFMA GEMM for xl|xr
  cast_x<<<(Nn * IN_CH / 4 + 255) / 256, 256, 0, stream>>>(x, xbf, Nn * IN_CH / 4);
  pack_w<<<(NPACK * IN_CH + 255) / 256, 256, 0, stream>>>(W_l, W_r, btb);
  dim3 ggrid(NPACK / 128, (Nn + 127) / 128);
  gemm_mfma<<<ggrid, 256, 0, stream>>>(xbf, btb, xl, xr, Nn);

  // 2) CSR by destination
  hipMemsetAsync(counts, 0, Nn * sizeof(int), stream);
  hist_dst<<<(E + 255) / 256, 256, 0, stream>>>(ei, counts, E);
  scan1<<<nb, 256, 0, stream>>>(counts, offsets, bsums, Nn);
  scan2<<<1, 256, 0, stream>>>(bsums, nb);
  scan3<<<nb, 256, 0, stream>>>(offsets, bsums, cursor, Nn);
  csr_fill<<<(E + 255) / 256, 256, 0, stream>>>(ei, cursor, csr_src, E);

  // 3) fused attention + softmax + aggregation (no atomics, 1 wave/node)
  gatv2_agg<<<(Nn + 3) / 4, 256, 0, stream>>>(xl, xr, att, offsets, counts,
                                              csr_src, agg, Nn);

  // 4) BatchNorm (train-mode batch stats) + ReLU
  hipMemsetAsync(gsum, 0, 2 * HC * sizeof(float), stream);
  bn_stats<<<200, 256, 0, stream>>>(agg, gsum, gsq, Nn);
  bn_final<<<1, HC, 0, stream>>>(gsum, gsq, mu, rs, 1.0f / (float)Nn);
  bn_apply<<<(Nn * HC / 4 + 255) / 256, 256, 0, stream>>>(agg, mu, rs, gamma, beta, y,
                                                          Nn * HC / 4);

  // 5) link scoring
  score<<<(EL + 3) / 4, 256, 0, stream>>>(y, eli, out, EL);
}

// Round 4
// 325.105 us; speedup vs baseline: 15.3980x; 1.2002x over previous
//
#include <hip/hip_runtime.h>
#include <hip/hip_bf16.h>
#include <cstdint>

#define IN_CH 512
#define HC    512   // HEADS*CH
#define HEADS 8
#define NPACK 1024  // W_l | W_r packed

typedef __attribute__((ext_vector_type(8))) short bf16x8;
typedef __attribute__((ext_vector_type(8))) ushort u16x8;
typedef __attribute__((ext_vector_type(4))) float f32x4;
typedef const __attribute__((address_space(1))) uint8_t* gaddr_t;
typedef __attribute__((address_space(3))) uint8_t* laddr_t;

__device__ inline ushort f2bf(float f) {  // round-to-nearest-even
  uint32_t u = __float_as_uint(f);
  return (ushort)((u + 0x7fffu + ((u >> 16) & 1u)) >> 16);
}
__device__ inline float bf2f(ushort u) {
  return __uint_as_float(((uint32_t)u) << 16);
}

// ---- cast x (fp32) -> bf16, vectorized -------------------------------------
__global__ void cast_x(const float* __restrict__ x, ushort* __restrict__ xb, int n4) {
  const int i = blockIdx.x * blockDim.x + threadIdx.x;
  if (i >= n4) return;
  const float4 v = ((const float4*)x)[i];
  ushort4 o;
  o.x = f2bf(v.x); o.y = f2bf(v.y); o.z = f2bf(v.z); o.w = f2bf(v.w);
  ((ushort4*)xb)[i] = o;
}

// ---- pack [W_l | W_r] transposed -> Bt[n][k] bf16 --------------------------
__global__ void pack_w(const float* __restrict__ Wl, const float* __restrict__ Wr,
                       ushort* __restrict__ bt) {
  const int i = blockIdx.x * blockDim.x + threadIdx.x;  // n*512 + k
  if (i >= NPACK * IN_CH) return;
  const int n = i >> 9, k = i & 511;
  const float v = (n < HC) ? Wl[(size_t)k * HC + n] : Wr[(size_t)k * HC + (n - HC)];
  bt[i] = f2bf(v);
}

// ---- bf16 MFMA GEMM: [M,1024] = xb[M,512] @ Bt^T -> xl (bf16) | xr (fp32) --
__global__ __launch_bounds__(256) void gemm_mfma(
    const ushort* __restrict__ xb, const ushort* __restrict__ bt,
    ushort* __restrict__ xlb, float* __restrict__ xr, int M) {
  __shared__ __align__(16) ushort As[128 * 32];  // [row][k], stride 32
  __shared__ __align__(16) ushort Bs[128 * 32];  // [col][k], stride 32
  const int wave = threadIdx.x >> 6, lane = threadIdx.x & 63;
  const int row0 = blockIdx.y * 128, col0 = blockIdx.x * 128;
  const int quad = lane >> 4, m16 = lane & 15;
  const int wrow = (wave >> 1) * 64, wcol = (wave & 1) * 64;
  const int srow = lane >> 2;        // staging: row within 16-row chunk
  const int scol = (lane & 3) * 8;   // staging: bf16 element offset in row
  const f32x4 zero = {0.f, 0.f, 0.f, 0.f};
  f32x4 acc[4][4];
  #pragma unroll
  for (int i = 0; i < 4; ++i)
    #pragma unroll
    for (int j = 0; j < 4; ++j) acc[i][j] = zero;

  for (int k0 = 0; k0 < IN_CH; k0 += 32) {
    #pragma unroll
    for (int c = 0; c < 2; ++c) {
      const int chunk = wave * 2 + c;  // 0..7, 16 rows each
      const ushort* ga = xb + (size_t)(row0 + chunk * 16 + srow) * IN_CH + k0 + scol;
      __builtin_amdgcn_global_load_lds((gaddr_t)ga, (laddr_t)(As + chunk * 512), 16, 0, 0);
      const ushort* gb = bt + (size_t)(col0 + chunk * 16 + srow) * IN_CH + k0 + scol;
      __builtin_amdgcn_global_load_lds((gaddr_t)gb, (laddr_t)(Bs + chunk * 512), 16, 0, 0);
    }
    __syncthreads();
    bf16x8 af[4], bfr[4];
    #pragma unroll
    for (int i = 0; i < 4; ++i)
      af[i] = *(const bf16x8*)(As + (wrow + i * 16 + m16) * 32 + quad * 8);
    #pragma unroll
    for (int j = 0; j < 4; ++j)
      bfr[j] = *(const bf16x8*)(Bs + (wcol + j * 16 + m16) * 32 + quad * 8);
    #pragma unroll
    for (int i = 0; i < 4; ++i)
      #pragma unroll
      for (int j = 0; j < 4; ++j)
        acc[i][j] = __builtin_amdgcn_mfma_f32_16x16x32_bf16(af[i], bfr[j], acc[i][j], 0, 0, 0);
    __syncthreads();
  }
  // epilogue: C/D layout col=lane&15, row=quad*4+reg. Block-uniform xl/xr split.
  const bool isL = (col0 < HC);
  #pragma unroll
  for (int i = 0; i < 4; ++i) {
    const int r = row0 + wrow + i * 16 + quad * 4;
    #pragma unroll
    for (int j = 0; j < 4; ++j) {
      const int cg = col0 + wcol + j * 16 + m16;
      #pragma unroll
      for (int t = 0; t < 4; ++t) {
        const int rr = r + t;
        if (rr < M) {
          if (isL) xlb[(size_t)rr * HC + cg] = f2bf(acc[i][j][t]);
          else     xr[(size_t)rr * HC + (cg - HC)] = acc[i][j][t];
        }
      }
    }
  }
}

// ---------------- CSR build: histogram -> scan -> fill ----------------------
__global__ void hist_dst(const int* __restrict__ ei, int* __restrict__ counts, int E) {
  const int e = blockIdx.x * blockDim.x + threadIdx.x;
  if (e < E) atomicAdd(&counts[ei[E + e]], 1);
}

__global__ void scan1(const int* __restrict__ counts, int* __restrict__ offsets,
                      int* __restrict__ bsums, int Nn) {
  __shared__ int tmp[256];
  const int t = threadIdx.x;
  const int i = blockIdx.x * 256 + t;
  const int v = (i < Nn) ? counts[i] : 0;
  tmp[t] = v;
  __syncthreads();
  for (int d = 1; d < 256; d <<= 1) {
    int add = (t >= d) ? tmp[t - d] : 0;
    __syncthreads();
    tmp[t] += add;
    __syncthreads();
  }
  if (i < Nn) offsets[i] = tmp[t] - v;  // exclusive
  if (t == 255) bsums[blockIdx.x] = tmp[255];
}

__global__ void scan2(int* __restrict__ bsums, int nb) {
  __shared__ int tmp[256];
  const int t = threadIdx.x;
  if (t < nb) tmp[t] = bsums[t];
  __syncthreads();
  if (t == 0) {
    int run = 0;
    for (int b = 0; b < nb; ++b) { int c = tmp[b]; tmp[b] = run; run += c; }
  }
  __syncthreads();
  if (t < nb) bsums[t] = tmp[t];
}

__global__ void scan3(int* __restrict__ offsets, const int* __restrict__ bsums,
                      int* __restrict__ cursor, int Nn) {
  const int i = blockIdx.x * blockDim.x + threadIdx.x;
  if (i < Nn) {
    const int o = offsets[i] + bsums[i >> 8];
    offsets[i] = o;
    cursor[i] = o;
  }
}

__global__ void csr_fill(const int* __restrict__ ei, int* __restrict__ cursor,
                         int* __restrict__ csr_src, int E) {
  const int e = blockIdx.x * blockDim.x + threadIdx.x;
  if (e < E) {
    const int pos = atomicAdd(&cursor[ei[E + e]], 1);
    csr_src[pos] = ei[e];
  }
}

// ------- fused GATv2: logits + softmax + weighted aggregation, 1 wave/node --
// bf16 xl gathers (16 B/lane), fp32 accumulate, software-pipelined edge loop.
__global__ __launch_bounds__(256) void gatv2_agg(
    const ushort* __restrict__ xlb, const float* xr, const float* __restrict__ att,
    const int* __restrict__ offsets, const int* __restrict__ counts,
    const int* __restrict__ csr_src, float* agg, int Nn) {
  const int node = blockIdx.x * 4 + (threadIdx.x >> 6);
  const int lane = threadIdx.x & 63;
  if (node >= Nn) return;
  const int start = offsets[node];
  const int deg   = counts[node];
  const float4* pr = (const float4*)(xr + (size_t)node * HC + lane * 8);
  const float4 r0 = pr[0], r1 = pr[1];
  const float4* pa = (const float4*)(att + lane * 8);
  const float4 t0 = pa[0], t1 = pa[1];
  float acc[8] = {};
  float densum = 0.f;
  auto lrelu = [](float v) { return v > 0.f ? v : 0.2f * v; };

  u16x8 vb = {};
  if (deg > 0) {
    const int s0 = csr_src[start];
    vb = *(const u16x8*)(xlb + (size_t)s0 * HC + lane * 8);
  }
  for (int i = 0; i < deg; ++i) {
    const u16x8 cur = vb;
    if (i + 1 < deg) {
      const int sn = csr_src[start + i + 1];
      vb = *(const u16x8*)(xlb + (size_t)sn * HC + lane * 8);
    }
    float a[8];
    #pragma unroll
    for (int c = 0; c < 8; ++c) a[c] = bf2f((ushort)cur[c]);
    float s = lrelu(a[0] + r0.x) * t0.x + lrelu(a[1] + r0.y) * t0.y +
              lrelu(a[2] + r0.z) * t0.z + lrelu(a[3] + r0.w) * t0.w +
              lrelu(a[4] + r1.x) * t1.x + lrelu(a[5] + r1.y) * t1.y +
              lrelu(a[6] + r1.z) * t1.z + lrelu(a[7] + r1.w) * t1.w;
    s += __shfl_xor(s, 1, 8);
    s += __shfl_xor(s, 2, 8);
    s += __shfl_xor(s, 4, 8);
    const float ea = __expf(s);
    densum += ea;
    #pragma unroll
    for (int c = 0; c < 8; ++c) acc[c] += ea * a[c];
  }
  const float inv = 1.0f / (densum + 1e-16f);
  float* pd = agg + (size_t)node * HC + lane * 8;
  *(float4*)(pd + 0) = make_float4(acc[0] * inv, acc[1] * inv, acc[2] * inv, acc[3] * inv);
  *(float4*)(pd + 4) = make_float4(acc[4] * inv, acc[5] * inv, acc[6] * inv, acc[7] * inv);
}

// ------------- BatchNorm stats: per-channel sum / sumsq ---------------------
__global__ void bn_stats(const float* __restrict__ agg, float* __restrict__ gsum,
                         float* __restrict__ gsq, int Nn) {
  const int t = threadIdx.x;  // 256
  const int rows_per_block = (Nn + gridDim.x - 1) / gridDim.x;
  const int r0 = blockIdx.x * rows_per_block;
  const int r1 = min(Nn, r0 + rows_per_block);
  float s0 = 0.f, s1 = 0.f, q0 = 0.f, q1 = 0.f;
  for (int r = r0; r < r1; ++r) {
    const float v0 = agg[(size_t)r * HC + t];
    const float v1 = agg[(size_t)r * HC + t + 256];
    s0 += v0; q0 += v0 * v0;
    s1 += v1; q1 += v1 * v1;
  }
  atomicAdd(&gsum[t], s0);
  atomicAdd(&gsum[t + 256], s1);
  atomicAdd(&gsq[t], q0);
  atomicAdd(&gsq[t + 256], q1);
}

__global__ void bn_final(const float* __restrict__ gsum, const float* __restrict__ gsq,
                         float* __restrict__ mu, float* __restrict__ rs, float invN) {
  const int c = threadIdx.x;  // 512
  const float m = gsum[c] * invN;
  const float v = gsq[c] * invN - m * m;
  mu[c] = m;
  rs[c] = rsqrtf(v + 1e-5f);
}

// ------------- BN apply + ReLU -> y (bf16) ----------------------------------
__global__ void bn_apply(const float* __restrict__ agg, const float* __restrict__ mu,
                         const float* __restrict__ rs, const float* __restrict__ gamma,
                         const float* __restrict__ beta, ushort* __restrict__ y, int total4) {
  const int i = blockIdx.x * blockDim.x + threadIdx.x;
  if (i >= total4) return;
  const int base = i << 2;
  const int c = base & (HC - 1);
  float4 v = *(const float4*)(agg + base);
  ushort4 o;
  o.x = f2bf(fmaxf(0.f, (v.x - mu[c + 0]) * rs[c + 0] * gamma[c + 0] + beta[c + 0]));
  o.y = f2bf(fmaxf(0.f, (v.y - mu[c + 1]) * rs[c + 1] * gamma[c + 1] + beta[c + 1]));
  o.z = f2bf(fmaxf(0.f, (v.z - mu[c + 2]) * rs[c + 2] * gamma[c + 2] + beta[c + 2]));
  o.w = f2bf(fmaxf(0.f, (v.w - mu[c + 3]) * rs[c + 3] * gamma[c + 3] + beta[c + 3]));
  *(ushort4*)(y + base) = o;
}

// ------------- link scoring: out[e] = dot(y[s], y[t]), bf16 gathers ---------
__global__ void score(const ushort* __restrict__ y, const int* __restrict__ eli,
                      float* __restrict__ out, int EL) {
  const int wave = blockIdx.x * (blockDim.x >> 6) + (threadIdx.x >> 6);
  const int lane = threadIdx.x & 63;
  if (wave >= EL) return;
  const int a = eli[wave];
  const int b = eli[EL + wave];
  const u16x8 ua = *(const u16x8*)(y + (size_t)a * HC + lane * 8);
  const u16x8 ub = *(const u16x8*)(y + (size_t)b * HC + lane * 8);
  float s = 0.f;
  #pragma unroll
  for (int c = 0; c < 8; ++c) s += bf2f((ushort)ua[c]) * bf2f((ushort)ub[c]);
  #pragma unroll
  for (int off = 32; off > 0; off >>= 1) s += __shfl_down(s, off, 64);
  if (lane == 0) out[wave] = s;
}

extern "C" void kernel_launch(void* const* d_in, const int* in_sizes, int n_in,
                              void* d_out, int out_size, void* d_ws, size_t ws_size,
                              hipStream_t stream) {
  const float* x     = (const float*)d_in[0];
  const int*   ei    = (const int*)d_in[1];
  const int*   eli   = (const int*)d_in[2];
  const float* W_l   = (const float*)d_in[3];
  const float* W_r   = (const float*)d_in[4];
  const float* att   = (const float*)d_in[5];
  // d_in[6] = bias: cancels exactly inside train-mode BatchNorm -> unused.
  const float* gamma = (const float*)d_in[7];
  const float* beta  = (const float*)d_in[8];
  float* out = (float*)d_out;

  const int Nn = in_sizes[0] / IN_CH;  // 20000
  const int E  = in_sizes[1] / 2;      // 320000
  const int EL = in_sizes[2] / 2;      // 100000

  ushort* xlb = (ushort*)d_ws;                     // Nn*HC bf16 (reused as y)
  float*  xr  = (float*)(xlb + (size_t)Nn * HC);   // Nn*HC fp32 (reused as agg)
  ushort* xbf = (ushort*)(xr + (size_t)Nn * HC);   // Nn*IN_CH bf16
  ushort* btb = xbf + (size_t)Nn * IN_CH;          // NPACK*IN_CH bf16
  // CSR + BN scratch aliases xbf (dead after gemm_mfma, stream-ordered):
  int* counts  = (int*)xbf;              // Nn
  int* offsets = counts + Nn;            // Nn
  int* cursor  = offsets + Nn;           // Nn
  int* bsums   = cursor + Nn;            // 256
  int* csr_src = bsums + 256;            // E
  float* gsum  = (float*)(csr_src + E);  // HC
  float* gsq   = gsum + HC;              // HC
  float* mu    = gsq + HC;               // HC
  float* rs    = mu + HC;                // HC
  float*  agg = xr;
  ushort* y   = xlb;  // xlb dead after gatv2_agg

  const int nb = (Nn + 255) / 256;

  // 1) casts + packed-transposed weights, one bf16 MFMA GEMM -> xlb | xr
  cast_x<<<(Nn * IN_CH / 4 + 255) / 256, 256, 0, stream>>>(x, xbf, Nn * IN_CH / 4);
  pack_w<<<(NPACK * IN_CH + 255) / 256, 256, 0, stream>>>(W_l, W_r, btb);
  dim3 ggrid(NPACK / 128, (Nn + 127) / 128);
  gemm_mfma<<<ggrid, 256, 0, stream>>>(xbf, btb, xlb, xr, Nn);

  // 2) CSR by destination
  hipMemsetAsync(counts, 0, Nn * sizeof(int), stream);
  hist_dst<<<(E + 255) / 256, 256, 0, stream>>>(ei, counts, E);
  scan1<<<nb, 256, 0, stream>>>(counts, offsets, bsums, Nn);
  scan2<<<1, 256, 0, stream>>>(bsums, nb);
  scan3<<<nb, 256, 0, stream>>>(offsets, bsums, cursor, Nn);
  csr_fill<<<(E + 255) / 256, 256, 0, stream>>>(ei, cursor, csr_src, E);

  // 3) fused attention + softmax + aggregation (no atomics, 1 wave/node)
  gatv2_agg<<<(Nn + 3) / 4, 256, 0, stream>>>(xlb, xr, att, offsets, counts,
                                              csr_src, agg, Nn);

  // 4) BatchNorm (train-mode batch stats) + ReLU -> bf16 y
  hipMemsetAsync(gsum, 0, 2 * HC * sizeof(float), stream);
  bn_stats<<<200, 256, 0, stream>>>(agg, gsum, gsq, Nn);
  bn_final<<<1, HC, 0, stream>>>(gsum, gsq, mu, rs, 1.0f / (float)Nn);
  bn_apply<<<(Nn * HC / 4 + 255) / 256, 256, 0, stream>>>(agg, mu, rs, gamma, beta, y,
                                                          Nn * HC / 4);

  // 5) link scoring (bf16 gathers, fp32 dot)
  score<<<(EL + 3) / 4, 256, 0, stream>>>(y, eli, out, EL);
}

// Round 5
// 320.092 us; speedup vs baseline: 15.6392x; 1.0157x over previous
//
#include <hip/hip_runtime.h>
#include <hip/hip_bf16.h>
#include <cstdint>

#define IN_CH 512
#define HC    512   // HEADS*CH
#define HEADS 8
#define NPACK 1024  // W_l | W_r packed

typedef __attribute__((ext_vector_type(8))) short bf16x8;
typedef __attribute__((ext_vector_type(8))) ushort u16x8;
typedef __attribute__((ext_vector_type(4))) float f32x4;
typedef const __attribute__((address_space(1))) uint8_t* gaddr_t;
typedef __attribute__((address_space(3))) uint8_t* laddr_t;

__device__ inline ushort f2bf(float f) {  // round-to-nearest-even
  uint32_t u = __float_as_uint(f);
  return (ushort)((u + 0x7fffu + ((u >> 16) & 1u)) >> 16);
}
__device__ inline float bf2f(ushort u) {
  return __uint_as_float(((uint32_t)u) << 16);
}

// ---- fused prep: cast x->bf16 | pack W^T bf16 | hist(dst) | hist(label s) --
__global__ void prep(const float* __restrict__ x, ushort* __restrict__ xb,
                     const float* __restrict__ Wl, const float* __restrict__ Wr,
                     ushort* __restrict__ bt,
                     const int* __restrict__ ei, int* __restrict__ counts,
                     const int* __restrict__ eli, int* __restrict__ counts2,
                     int n4, int E, int EL, int nbc, int nbp, int nbh) {
  const int b = blockIdx.x;
  if (b < nbc) {
    const int i = b * 256 + threadIdx.x;
    if (i < n4) {
      const float4 v = ((const float4*)x)[i];
      ushort4 o;
      o.x = f2bf(v.x); o.y = f2bf(v.y); o.z = f2bf(v.z); o.w = f2bf(v.w);
      ((ushort4*)xb)[i] = o;
    }
  } else if (b < nbc + nbp) {
    const int i = (b - nbc) * 256 + threadIdx.x;
    if (i < NPACK * IN_CH) {
      const int n = i >> 9, k = i & 511;
      const float v = (n < HC) ? Wl[(size_t)k * HC + n] : Wr[(size_t)k * HC + (n - HC)];
      bt[i] = f2bf(v);
    }
  } else if (b < nbc + nbp + nbh) {
    const int e = (b - nbc - nbp) * 256 + threadIdx.x;
    if (e < E) atomicAdd(&counts[ei[E + e]], 1);
  } else {
    const int e = (b - nbc - nbp - nbh) * 256 + threadIdx.x;
    if (e < EL) atomicAdd(&counts2[eli[e]], 1);
  }
}

// ---- bf16 MFMA GEMM: [M,1024] = xb[M,512] @ Bt^T -> xl (bf16) | xr (fp32) --
__global__ __launch_bounds__(256) void gemm_mfma(
    const ushort* __restrict__ xb, const ushort* __restrict__ bt,
    ushort* __restrict__ xlb, float* __restrict__ xr, int M) {
  __shared__ __align__(16) ushort As[128 * 32];  // [row][k], stride 32
  __shared__ __align__(16) ushort Bs[128 * 32];  // [col][k], stride 32
  const int wave = threadIdx.x >> 6, lane = threadIdx.x & 63;
  const int row0 = blockIdx.y * 128, col0 = blockIdx.x * 128;
  const int quad = lane >> 4, m16 = lane & 15;
  const int wrow = (wave >> 1) * 64, wcol = (wave & 1) * 64;
  const int srow = lane >> 2;
  const int scol = (lane & 3) * 8;
  const f32x4 zero = {0.f, 0.f, 0.f, 0.f};
  f32x4 acc[4][4];
  #pragma unroll
  for (int i = 0; i < 4; ++i)
    #pragma unroll
    for (int j = 0; j < 4; ++j) acc[i][j] = zero;

  for (int k0 = 0; k0 < IN_CH; k0 += 32) {
    #pragma unroll
    for (int c = 0; c < 2; ++c) {
      const int chunk = wave * 2 + c;
      const ushort* ga = xb + (size_t)(row0 + chunk * 16 + srow) * IN_CH + k0 + scol;
      __builtin_amdgcn_global_load_lds((gaddr_t)ga, (laddr_t)(As + chunk * 512), 16, 0, 0);
      const ushort* gb = bt + (size_t)(col0 + chunk * 16 + srow) * IN_CH + k0 + scol;
      __builtin_amdgcn_global_load_lds((gaddr_t)gb, (laddr_t)(Bs + chunk * 512), 16, 0, 0);
    }
    __syncthreads();
    bf16x8 af[4], bfr[4];
    #pragma unroll
    for (int i = 0; i < 4; ++i)
      af[i] = *(const bf16x8*)(As + (wrow + i * 16 + m16) * 32 + quad * 8);
    #pragma unroll
    for (int j = 0; j < 4; ++j)
      bfr[j] = *(const bf16x8*)(Bs + (wcol + j * 16 + m16) * 32 + quad * 8);
    #pragma unroll
    for (int i = 0; i < 4; ++i)
      #pragma unroll
      for (int j = 0; j < 4; ++j)
        acc[i][j] = __builtin_amdgcn_mfma_f32_16x16x32_bf16(af[i], bfr[j], acc[i][j], 0, 0, 0);
    __syncthreads();
  }
  const bool isL = (col0 < HC);
  #pragma unroll
  for (int i = 0; i < 4; ++i) {
    const int r = row0 + wrow + i * 16 + quad * 4;
    #pragma unroll
    for (int j = 0; j < 4; ++j) {
      const int cg = col0 + wcol + j * 16 + m16;
      #pragma unroll
      for (int t = 0; t < 4; ++t) {
        const int rr = r + t;
        if (rr < M) {
          if (isL) xlb[(size_t)rr * HC + cg] = f2bf(acc[i][j][t]);
          else     xr[(size_t)rr * HC + (cg - HC)] = acc[i][j][t];
        }
      }
    }
  }
}

// ---------------- dual-CSR scan chain (graph + label) -----------------------
__global__ void scan1(const int* __restrict__ cA, int* __restrict__ oA, int* __restrict__ bA,
                      const int* __restrict__ cB, int* __restrict__ oB, int* __restrict__ bB,
                      int Nn, int nb) {
  const int half = (blockIdx.x >= nb) ? 1 : 0;
  const int blk  = blockIdx.x - half * nb;
  const int* counts = half ? cB : cA;
  int* offsets = half ? oB : oA;
  int* bsums   = half ? bB : bA;
  __shared__ int tmp[256];
  const int t = threadIdx.x;
  const int i = blk * 256 + t;
  const int v = (i < Nn) ? counts[i] : 0;
  tmp[t] = v;
  __syncthreads();
  for (int d = 1; d < 256; d <<= 1) {
    int add = (t >= d) ? tmp[t - d] : 0;
    __syncthreads();
    tmp[t] += add;
    __syncthreads();
  }
  if (i < Nn) offsets[i] = tmp[t] - v;  // exclusive
  if (t == 255) bsums[blk] = tmp[255];
}

__global__ void scan2(int* __restrict__ bA, int* __restrict__ bB, int nb) {
  int* bsums = blockIdx.x ? bB : bA;
  __shared__ int tmp[256];
  const int t = threadIdx.x;
  if (t < nb) tmp[t] = bsums[t];
  __syncthreads();
  if (t == 0) {
    int run = 0;
    for (int b = 0; b < nb; ++b) { int c = tmp[b]; tmp[b] = run; run += c; }
  }
  __syncthreads();
  if (t < nb) bsums[t] = tmp[t];
}

__global__ void scan3(int* __restrict__ oA, const int* __restrict__ bA, int* __restrict__ curA,
                      int* __restrict__ oB, const int* __restrict__ bB, int* __restrict__ curB,
                      int Nn, int nb) {
  const int half = (blockIdx.x >= nb) ? 1 : 0;
  const int blk  = blockIdx.x - half * nb;
  int* offsets = half ? oB : oA;
  const int* bsums = half ? bB : bA;
  int* cursor  = half ? curB : curA;
  const int i = blk * 256 + threadIdx.x;
  if (i < Nn) {
    const int o = offsets[i] + bsums[i >> 8];
    offsets[i] = o;
    cursor[i] = o;
  }
}

__global__ void csr_fill(const int* __restrict__ ei, int* __restrict__ cursor,
                         int* __restrict__ csr_src,
                         const int* __restrict__ eli, int* __restrict__ cursor2,
                         int* __restrict__ csr_t, int* __restrict__ csr_eid,
                         int E, int EL, int nbE) {
  const int b = blockIdx.x;
  if (b < nbE) {
    const int e = b * 256 + threadIdx.x;
    if (e < E) {
      const int pos = atomicAdd(&cursor[ei[E + e]], 1);
      csr_src[pos] = ei[e];
    }
  } else {
    const int e = (b - nbE) * 256 + threadIdx.x;
    if (e < EL) {
      const int pos = atomicAdd(&cursor2[eli[e]], 1);
      csr_t[pos] = eli[EL + e];
      csr_eid[pos] = e;
    }
  }
}

// ------- fused GATv2: logits + softmax + aggregation, 1 wave/node -----------
// bf16 xl gathers, fp32 accumulate, prefetch-depth-2 pipelined edge loop.
__global__ __launch_bounds__(256) void gatv2_agg(
    const ushort* __restrict__ xlb, const float* xr, const float* __restrict__ att,
    const int* __restrict__ offsets, const int* __restrict__ counts,
    const int* __restrict__ csr_src, float* agg, int Nn) {
  const int node = blockIdx.x * 4 + (threadIdx.x >> 6);
  const int lane = threadIdx.x & 63;
  if (node >= Nn) return;
  const int start = offsets[node];
  const int deg   = counts[node];
  float rv[8], tv[8];
  {
    const float4* pr = (const float4*)(xr + (size_t)node * HC + lane * 8);
    const float4 r0 = pr[0], r1 = pr[1];
    rv[0]=r0.x; rv[1]=r0.y; rv[2]=r0.z; rv[3]=r0.w;
    rv[4]=r1.x; rv[5]=r1.y; rv[6]=r1.z; rv[7]=r1.w;
    const float4* pa = (const float4*)(att + lane * 8);
    const float4 t0 = pa[0], t1 = pa[1];
    tv[0]=t0.x; tv[1]=t0.y; tv[2]=t0.z; tv[3]=t0.w;
    tv[4]=t1.x; tv[5]=t1.y; tv[6]=t1.z; tv[7]=t1.w;
  }
  float acc[8] = {};
  float densum = 0.f;
  const int* ps = csr_src + start;
  auto row = [&](int idx) {
    return *(const u16x8*)(xlb + (size_t)ps[idx] * HC + lane * 8);
  };
  auto body = [&](const u16x8 cur) {
    float a[8];
    #pragma unroll
    for (int c = 0; c < 8; ++c) a[c] = bf2f((ushort)cur[c]);
    float s = 0.f;
    #pragma unroll
    for (int c = 0; c < 8; ++c) {
      const float v = a[c] + rv[c];
      s += fmaxf(v, 0.2f * v) * tv[c];  // leaky_relu(v,0.2) == max(v,0.2v)
    }
    s += __shfl_xor(s, 1, 8);
    s += __shfl_xor(s, 2, 8);
    s += __shfl_xor(s, 4, 8);
    const float ea = __expf(s);
    densum += ea;
    #pragma unroll
    for (int c = 0; c < 8; ++c) acc[c] += ea * a[c];
  };

  u16x8 v0 = {}, v1 = {};
  if (deg > 0) v0 = row(0);
  if (deg > 1) v1 = row(1);
  int i = 0;
  for (; i + 2 <= deg; i += 2) {
    const u16x8 c0 = v0;
    if (i + 2 < deg) v0 = row(i + 2);
    body(c0);
    const u16x8 c1 = v1;
    if (i + 3 < deg) v1 = row(i + 3);
    body(c1);
  }
  if (i < deg) body(v0);

  const float inv = 1.0f / (densum + 1e-16f);
  float* pd = agg + (size_t)node * HC + lane * 8;
  *(float4*)(pd + 0) = make_float4(acc[0] * inv, acc[1] * inv, acc[2] * inv, acc[3] * inv);
  *(float4*)(pd + 4) = make_float4(acc[4] * inv, acc[5] * inv, acc[6] * inv, acc[7] * inv);
}

// ------------- BatchNorm stats: per-channel sum / sumsq ---------------------
__global__ void bn_stats(const float* __restrict__ agg, float* __restrict__ gsum,
                         float* __restrict__ gsq, int Nn) {
  const int t = threadIdx.x;  // 256
  const int rows_per_block = (Nn + gridDim.x - 1) / gridDim.x;
  const int r0 = blockIdx.x * rows_per_block;
  const int r1 = min(Nn, r0 + rows_per_block);
  float s0 = 0.f, s1 = 0.f, q0 = 0.f, q1 = 0.f;
  for (int r = r0; r < r1; ++r) {
    const float v0 = agg[(size_t)r * HC + t];
    const float v1 = agg[(size_t)r * HC + t + 256];
    s0 += v0; q0 += v0 * v0;
    s1 += v1; q1 += v1 * v1;
  }
  atomicAdd(&gsum[t], s0);
  atomicAdd(&gsum[t + 256], s1);
  atomicAdd(&gsq[t], q0);
  atomicAdd(&gsq[t + 256], q1);
}

__global__ void bn_final(const float* __restrict__ gsum, const float* __restrict__ gsq,
                         float* __restrict__ mu, float* __restrict__ rs, float invN) {
  const int c = threadIdx.x;  // 512
  const float m = gsum[c] * invN;
  const float v = gsq[c] * invN - m * m;
  mu[c] = m;
  rs[c] = rsqrtf(v + 1e-5f);
}

// ------------- BN apply + ReLU -> y (bf16) ----------------------------------
__global__ void bn_apply(const float* __restrict__ agg, const float* __restrict__ mu,
                         const float* __restrict__ rs, const float* __restrict__ gamma,
                         const float* __restrict__ beta, ushort* __restrict__ y, int total4) {
  const int i = blockIdx.x * blockDim.x + threadIdx.x;
  if (i >= total4) return;
  const int base = i << 2;
  const int c = base & (HC - 1);
  float4 v = *(const float4*)(agg + base);
  ushort4 o;
  o.x = f2bf(fmaxf(0.f, (v.x - mu[c + 0]) * rs[c + 0] * gamma[c + 0] + beta[c + 0]));
  o.y = f2bf(fmaxf(0.f, (v.y - mu[c + 1]) * rs[c + 1] * gamma[c + 1] + beta[c + 1]));
  o.z = f2bf(fmaxf(0.f, (v.z - mu[c + 2]) * rs[c + 2] * gamma[c + 2] + beta[c + 2]));
  o.w = f2bf(fmaxf(0.f, (v.w - mu[c + 3]) * rs[c + 3] * gamma[c + 3] + beta[c + 3]));
  *(ushort4*)(y + base) = o;
}

// ------------- source-grouped link scoring: 1 wave/source node --------------
// y[s] loaded once to regs; only y[t] gathered per edge (prefetch-2).
__global__ __launch_bounds__(256) void score_g(
    const ushort* __restrict__ y, const int* __restrict__ off2,
    const int* __restrict__ cnt2, const int* __restrict__ csr_t,
    const int* __restrict__ csr_eid, float* __restrict__ out, int Nn) {
  const int node = blockIdx.x * 4 + (threadIdx.x >> 6);
  const int lane = threadIdx.x & 63;
  if (node >= Nn) return;
  const int start = off2[node];
  const int deg   = cnt2[node];
  if (deg == 0) return;
  float a[8];
  {
    const u16x8 us = *(const u16x8*)(y + (size_t)node * HC + lane * 8);
    #pragma unroll
    for (int c = 0; c < 8; ++c) a[c] = bf2f((ushort)us[c]);
  }
  const int* pt = csr_t + start;
  const int* pe = csr_eid + start;
  auto row = [&](int idx) {
    return *(const u16x8*)(y + (size_t)pt[idx] * HC + lane * 8);
  };
  auto emit = [&](const u16x8 ut, int eid) {
    float s = 0.f;
    #pragma unroll
    for (int c = 0; c < 8; ++c) s += a[c] * bf2f((ushort)ut[c]);
    #pragma unroll
    for (int off = 32; off > 0; off >>= 1) s += __shfl_down(s, off, 64);
    if (lane == 0) out[eid] = s;
  };
  u16x8 v0 = {}, v1 = {};
  v0 = row(0);
  if (deg > 1) v1 = row(1);
  int j = 0;
  for (; j + 2 <= deg; j += 2) {
    const u16x8 c0 = v0;
    if (j + 2 < deg) v0 = row(j + 2);
    emit(c0, pe[j]);
    const u16x8 c1 = v1;
    if (j + 3 < deg) v1 = row(j + 3);
    emit(c1, pe[j + 1]);
  }
  if (j < deg) emit(v0, pe[j]);
}

extern "C" void kernel_launch(void* const* d_in, const int* in_sizes, int n_in,
                              void* d_out, int out_size, void* d_ws, size_t ws_size,
                              hipStream_t stream) {
  const float* x     = (const float*)d_in[0];
  const int*   ei    = (const int*)d_in[1];
  const int*   eli   = (const int*)d_in[2];
  const float* W_l   = (const float*)d_in[3];
  const float* W_r   = (const float*)d_in[4];
  const float* att   = (const float*)d_in[5];
  // d_in[6] = bias: cancels exactly inside train-mode BatchNorm -> unused.
  const float* gamma = (const float*)d_in[7];
  const float* beta  = (const float*)d_in[8];
  float* out = (float*)d_out;

  const int Nn = in_sizes[0] / IN_CH;  // 20000
  const int E  = in_sizes[1] / 2;      // 320000
  const int EL = in_sizes[2] / 2;      // 100000

  // ---- workspace layout (no aliasing across live ranges except agg/y) ----
  ushort* xlb = (ushort*)d_ws;                     // Nn*HC bf16 (reused as y)
  float*  xr  = (float*)(xlb + (size_t)Nn * HC);   // Nn*HC fp32 (reused as agg)
  ushort* xbf = (ushort*)(xr + (size_t)Nn * HC);   // Nn*IN_CH bf16
  ushort* btb = xbf + (size_t)Nn * IN_CH;          // NPACK*IN_CH bf16
  int* counts   = (int*)(btb + (size_t)NPACK * IN_CH);  // Nn ┐ single
  int* counts2  = counts + Nn;                          // Nn │ memset
  float* gsum   = (float*)(counts2 + Nn);               // HC │ region
  float* gsq    = gsum + HC;                            // HC ┘
  int* offsets  = (int*)(gsq + HC);     // Nn
  int* cursor   = offsets + Nn;         // Nn
  int* bsumsA   = cursor + Nn;          // 256
  int* offsets2 = bsumsA + 256;         // Nn
  int* cursor2  = offsets2 + Nn;        // Nn
  int* bsumsB   = cursor2 + Nn;         // 256
  int* csr_src  = bsumsB + 256;         // E
  int* csr_t    = csr_src + E;          // EL
  int* csr_eid  = csr_t + EL;           // EL
  float* mu     = (float*)(csr_eid + EL);  // HC
  float* rs     = mu + HC;                 // HC
  float*  agg = xr;
  ushort* y   = xlb;  // xlb dead after gatv2_agg

  const int nb  = (Nn + 255) / 256;           // scan blocks per CSR (79)
  const int nbc = (Nn * IN_CH / 4 + 255) / 256;
  const int nbp = (NPACK * IN_CH + 255) / 256;
  const int nbh = (E + 255) / 256;
  const int nbh2 = (EL + 255) / 256;

  // 0) one memset: counts | counts2 | gsum | gsq
  hipMemsetAsync(counts, 0, (2 * (size_t)Nn + 2 * HC) * sizeof(int), stream);

  // 1) fused prep: cast + pack + both histograms
  prep<<<nbc + nbp + nbh + nbh2, 256, 0, stream>>>(
      x, xbf, W_l, W_r, btb, ei, counts, eli, counts2,
      Nn * IN_CH / 4, E, EL, nbc, nbp, nbh);

  // 2) one bf16 MFMA GEMM -> xlb | xr
  dim3 ggrid(NPACK / 128, (Nn + 127) / 128);
  gemm_mfma<<<ggrid, 256, 0, stream>>>(xbf, btb, xlb, xr, Nn);

  // 3) dual CSR (graph by dst, labels by src)
  scan1<<<2 * nb, 256, 0, stream>>>(counts, offsets, bsumsA,
                                    counts2, offsets2, bsumsB, Nn, nb);
  scan2<<<2, 256, 0, stream>>>(bsumsA, bsumsB, nb);
  scan3<<<2 * nb, 256, 0, stream>>>(offsets, bsumsA, cursor,
                                    offsets2, bsumsB, cursor2, Nn, nb);
  csr_fill<<<nbh + nbh2, 256, 0, stream>>>(ei, cursor, csr_src,
                                           eli, cursor2, csr_t, csr_eid, E, EL, nbh);

  // 4) fused attention + softmax + aggregation (no atomics, 1 wave/node)
  gatv2_agg<<<(Nn + 3) / 4, 256, 0, stream>>>(xlb, xr, att, offsets, counts,
                                              csr_src, agg, Nn);

  // 5) BatchNorm (train-mode batch stats) + ReLU -> bf16 y
  bn_stats<<<200, 256, 0, stream>>>(agg, gsum, gsq, Nn);
  bn_final<<<1, HC, 0, stream>>>(gsum, gsq, mu, rs, 1.0f / (float)Nn);
  bn_apply<<<(Nn * HC / 4 + 255) / 256, 256, 0, stream>>>(agg, mu, rs, gamma, beta, y,
                                                          Nn * HC / 4);

  // 6) source-grouped link scoring
  score_g<<<(Nn + 3) / 4, 256, 0, stream>>>(y, offsets2, counts2, csr_t, csr_eid,
                                            out, Nn);
}

// Round 6
// 318.603 us; speedup vs baseline: 15.7122x; 1.0047x over previous
//
#include <hip/hip_runtime.h>
#include <hip/hip_bf16.h>
#include <cstdint>

#define IN_CH 512
#define HC    512   // HEADS*CH
#define HEADS 8
#define NPACK 1024  // W_l | W_r packed

typedef __attribute__((ext_vector_type(8))) short bf16x8;
typedef __attribute__((ext_vector_type(8))) ushort u16x8;
typedef __attribute__((ext_vector_type(4))) float f32x4;
typedef const __attribute__((address_space(1))) uint8_t* gaddr_t;
typedef __attribute__((address_space(3))) uint8_t* laddr_t;

__device__ inline ushort f2bf(float f) {  // round-to-nearest-even
  uint32_t u = __float_as_uint(f);
  return (ushort)((u + 0x7fffu + ((u >> 16) & 1u)) >> 16);
}
__device__ inline float bf2f(ushort u) {
  return __uint_as_float(((uint32_t)u) << 16);
}

// ---- fused prep: cast x->bf16 | pack W^T bf16 | hist(dst) | hist(label s) --
__global__ void prep(const float* __restrict__ x, ushort* __restrict__ xb,
                     const float* __restrict__ Wl, const float* __restrict__ Wr,
                     ushort* __restrict__ bt,
                     const int* __restrict__ ei, int* __restrict__ counts,
                     const int* __restrict__ eli, int* __restrict__ counts2,
                     int n4, int E, int EL, int nbc, int nbp, int nbh) {
  const int b = blockIdx.x;
  if (b < nbc) {
    const int i = b * 256 + threadIdx.x;
    if (i < n4) {
      const float4 v = ((const float4*)x)[i];
      ushort4 o;
      o.x = f2bf(v.x); o.y = f2bf(v.y); o.z = f2bf(v.z); o.w = f2bf(v.w);
      ((ushort4*)xb)[i] = o;
    }
  } else if (b < nbc + nbp) {
    const int i = (b - nbc) * 256 + threadIdx.x;
    if (i < NPACK * IN_CH) {
      const int n = i >> 9, k = i & 511;
      const float v = (n < HC) ? Wl[(size_t)k * HC + n] : Wr[(size_t)k * HC + (n - HC)];
      bt[i] = f2bf(v);
    }
  } else if (b < nbc + nbp + nbh) {
    const int e = (b - nbc - nbp) * 256 + threadIdx.x;
    if (e < E) atomicAdd(&counts[ei[E + e]], 1);
  } else {
    const int e = (b - nbc - nbp - nbh) * 256 + threadIdx.x;
    if (e < EL) atomicAdd(&counts2[eli[e]], 1);
  }
}

// ---- bf16 MFMA GEMM: [M,1024] = xb[M,512] @ Bt^T -> xlb | xrb (both bf16) --
__global__ __launch_bounds__(256) void gemm_mfma(
    const ushort* __restrict__ xb, const ushort* __restrict__ bt,
    ushort* __restrict__ xlb, ushort* __restrict__ xrb, int M) {
  __shared__ __align__(16) ushort As[128 * 32];  // [row][k], stride 32
  __shared__ __align__(16) ushort Bs[128 * 32];  // [col][k], stride 32
  const int wave = threadIdx.x >> 6, lane = threadIdx.x & 63;
  const int row0 = blockIdx.y * 128, col0 = blockIdx.x * 128;
  const int quad = lane >> 4, m16 = lane & 15;
  const int wrow = (wave >> 1) * 64, wcol = (wave & 1) * 64;
  const int srow = lane >> 2;
  const int scol = (lane & 3) * 8;
  const f32x4 zero = {0.f, 0.f, 0.f, 0.f};
  f32x4 acc[4][4];
  #pragma unroll
  for (int i = 0; i < 4; ++i)
    #pragma unroll
    for (int j = 0; j < 4; ++j) acc[i][j] = zero;

  for (int k0 = 0; k0 < IN_CH; k0 += 32) {
    #pragma unroll
    for (int c = 0; c < 2; ++c) {
      const int chunk = wave * 2 + c;
      const ushort* ga = xb + (size_t)(row0 + chunk * 16 + srow) * IN_CH + k0 + scol;
      __builtin_amdgcn_global_load_lds((gaddr_t)ga, (laddr_t)(As + chunk * 512), 16, 0, 0);
      const ushort* gb = bt + (size_t)(col0 + chunk * 16 + srow) * IN_CH + k0 + scol;
      __builtin_amdgcn_global_load_lds((gaddr_t)gb, (laddr_t)(Bs + chunk * 512), 16, 0, 0);
    }
    __syncthreads();
    bf16x8 af[4], bfr[4];
    #pragma unroll
    for (int i = 0; i < 4; ++i)
      af[i] = *(const bf16x8*)(As + (wrow + i * 16 + m16) * 32 + quad * 8);
    #pragma unroll
    for (int j = 0; j < 4; ++j)
      bfr[j] = *(const bf16x8*)(Bs + (wcol + j * 16 + m16) * 32 + quad * 8);
    #pragma unroll
    for (int i = 0; i < 4; ++i)
      #pragma unroll
      for (int j = 0; j < 4; ++j)
        acc[i][j] = __builtin_amdgcn_mfma_f32_16x16x32_bf16(af[i], bfr[j], acc[i][j], 0, 0, 0);
    __syncthreads();
  }
  const bool isL = (col0 < HC);
  ushort* dst = isL ? xlb : xrb;
  const int cbase = isL ? col0 : (col0 - HC);
  #pragma unroll
  for (int i = 0; i < 4; ++i) {
    const int r = row0 + wrow + i * 16 + quad * 4;
    #pragma unroll
    for (int j = 0; j < 4; ++j) {
      const int cg = cbase + wcol + j * 16 + m16;
      #pragma unroll
      for (int t = 0; t < 4; ++t) {
        const int rr = r + t;
        if (rr < M) dst[(size_t)rr * HC + cg] = f2bf(acc[i][j][t]);
      }
    }
  }
}

// ---------------- dual-CSR scan chain (graph + label) -----------------------
__global__ void scan1(const int* __restrict__ cA, int* __restrict__ oA, int* __restrict__ bA,
                      const int* __restrict__ cB, int* __restrict__ oB, int* __restrict__ bB,
                      int Nn, int nb) {
  const int half = (blockIdx.x >= nb) ? 1 : 0;
  const int blk  = blockIdx.x - half * nb;
  const int* counts = half ? cB : cA;
  int* offsets = half ? oB : oA;
  int* bsums   = half ? bB : bA;
  __shared__ int tmp[256];
  const int t = threadIdx.x;
  const int i = blk * 256 + t;
  const int v = (i < Nn) ? counts[i] : 0;
  tmp[t] = v;
  __syncthreads();
  for (int d = 1; d < 256; d <<= 1) {
    int add = (t >= d) ? tmp[t - d] : 0;
    __syncthreads();
    tmp[t] += add;
    __syncthreads();
  }
  if (i < Nn) offsets[i] = tmp[t] - v;  // exclusive
  if (t == 255) bsums[blk] = tmp[255];
}

// scan3 with inline block-prefix (folds old scan2): wave 0 sums bsums[0..blk)
__global__ void scan3(int* __restrict__ oA, const int* __restrict__ bA, int* __restrict__ curA,
                      int* __restrict__ oB, const int* __restrict__ bB, int* __restrict__ curB,
                      int Nn, int nb) {
  const int half = (blockIdx.x >= nb) ? 1 : 0;
  const int blk  = blockIdx.x - half * nb;
  int* offsets = half ? oB : oA;
  const int* bsums = half ? bB : bA;
  int* cursor  = half ? curB : curA;
  __shared__ int pref;
  if (threadIdx.x < 64) {
    int s = 0;
    for (int b = threadIdx.x; b < blk; b += 64) s += bsums[b];
    #pragma unroll
    for (int off = 32; off > 0; off >>= 1) s += __shfl_down(s, off, 64);
    if (threadIdx.x == 0) pref = s;
  }
  __syncthreads();
  const int i = blk * 256 + threadIdx.x;
  if (i < Nn) {
    const int o = offsets[i] + pref;
    offsets[i] = o;
    cursor[i] = o;
  }
}

__global__ void csr_fill(const int* __restrict__ ei, int* __restrict__ cursor,
                         int* __restrict__ csr_src,
                         const int* __restrict__ eli, int* __restrict__ cursor2,
                         int* __restrict__ csr_t, int* __restrict__ csr_eid,
                         int E, int EL, int nbE) {
  const int b = blockIdx.x;
  if (b < nbE) {
    const int e = b * 256 + threadIdx.x;
    if (e < E) {
      const int pos = atomicAdd(&cursor[ei[E + e]], 1);
      csr_src[pos] = ei[e];
    }
  } else {
    const int e = (b - nbE) * 256 + threadIdx.x;
    if (e < EL) {
      const int pos = atomicAdd(&cursor2[eli[e]], 1);
      csr_t[pos] = eli[EL + e];
      csr_eid[pos] = e;
    }
  }
}

// ------- fused GATv2: logits + softmax + aggregation, 1 wave/node -----------
// bf16 gathers, fp32 accumulate, prefetch-depth-4 pipelined edge loop.
// agg (bf16) may alias xrb: wave reads only xrb[node] up front, writes only
// agg[node] at the end -> row-local, safe.
__global__ __launch_bounds__(256) void gatv2_agg(
    const ushort* __restrict__ xlb, const ushort* xrb, const float* __restrict__ att,
    const int* __restrict__ offsets, const int* __restrict__ counts,
    const int* __restrict__ csr_src, ushort* agg, int Nn) {
  const int node = blockIdx.x * 4 + (threadIdx.x >> 6);
  const int lane = threadIdx.x & 63;
  if (node >= Nn) return;
  const int start = offsets[node];
  const int deg   = counts[node];
  float rv[8], tv[8];
  {
    const u16x8 ur = *(const u16x8*)(xrb + (size_t)node * HC + lane * 8);
    #pragma unroll
    for (int c = 0; c < 8; ++c) rv[c] = bf2f((ushort)ur[c]);
    const float4* pa = (const float4*)(att + lane * 8);
    const float4 t0 = pa[0], t1 = pa[1];
    tv[0]=t0.x; tv[1]=t0.y; tv[2]=t0.z; tv[3]=t0.w;
    tv[4]=t1.x; tv[5]=t1.y; tv[6]=t1.z; tv[7]=t1.w;
  }
  float acc[8] = {};
  float densum = 0.f;
  const int* ps = csr_src + start;
  auto row = [&](int idx) {
    return *(const u16x8*)(xlb + (size_t)ps[idx] * HC + lane * 8);
  };
  auto body = [&](const u16x8 cur) {
    float a[8];
    #pragma unroll
    for (int c = 0; c < 8; ++c) a[c] = bf2f((ushort)cur[c]);
    float s = 0.f;
    #pragma unroll
    for (int c = 0; c < 8; ++c) {
      const float v = a[c] + rv[c];
      s += fmaxf(v, 0.2f * v) * tv[c];  // leaky_relu(v,0.2) == max(v,0.2v)
    }
    s += __shfl_xor(s, 1, 8);
    s += __shfl_xor(s, 2, 8);
    s += __shfl_xor(s, 4, 8);
    const float ea = __expf(s);
    densum += ea;
    #pragma unroll
    for (int c = 0; c < 8; ++c) acc[c] += ea * a[c];
  };

  u16x8 b0 = {}, b1 = {}, b2 = {}, b3 = {};
  if (deg > 0) b0 = row(0);
  if (deg > 1) b1 = row(1);
  if (deg > 2) b2 = row(2);
  if (deg > 3) b3 = row(3);
  int i = 0;
  for (; i + 4 <= deg; i += 4) {
    const u16x8 c0 = b0; if (i + 4 < deg) b0 = row(i + 4);
    const u16x8 c1 = b1; if (i + 5 < deg) b1 = row(i + 5);
    const u16x8 c2 = b2; if (i + 6 < deg) b2 = row(i + 6);
    const u16x8 c3 = b3; if (i + 7 < deg) b3 = row(i + 7);
    body(c0); body(c1); body(c2); body(c3);
  }
  const int r = deg - i;
  if (r > 0) body(b0);
  if (r > 1) body(b1);
  if (r > 2) body(b2);

  const float inv = 1.0f / (densum + 1e-16f);
  ushort* pd = agg + (size_t)node * HC + lane * 8;
  ushort4 o0, o1;
  o0.x = f2bf(acc[0] * inv); o0.y = f2bf(acc[1] * inv);
  o0.z = f2bf(acc[2] * inv); o0.w = f2bf(acc[3] * inv);
  o1.x = f2bf(acc[4] * inv); o1.y = f2bf(acc[5] * inv);
  o1.z = f2bf(acc[6] * inv); o1.w = f2bf(acc[7] * inv);
  *(ushort4*)(pd + 0) = o0;
  *(ushort4*)(pd + 4) = o1;
}

// ------------- BatchNorm stats: per-channel sum / sumsq (bf16 agg) ----------
__global__ void bn_stats(const ushort* __restrict__ agg, float* __restrict__ gsum,
                         float* __restrict__ gsq, int Nn) {
  const int t = threadIdx.x;  // 256; thread covers channels 2t, 2t+1
  const int rows_per_block = (Nn + gridDim.x - 1) / gridDim.x;
  const int r0 = blockIdx.x * rows_per_block;
  const int r1 = min(Nn, r0 + rows_per_block);
  float s0 = 0.f, s1 = 0.f, q0 = 0.f, q1 = 0.f;
  for (int r = r0; r < r1; ++r) {
    const ushort2 u = ((const ushort2*)(agg + (size_t)r * HC))[t];
    const float v0 = bf2f(u.x), v1 = bf2f(u.y);
    s0 += v0; q0 += v0 * v0;
    s1 += v1; q1 += v1 * v1;
  }
  atomicAdd(&gsum[2 * t], s0);
  atomicAdd(&gsum[2 * t + 1], s1);
  atomicAdd(&gsq[2 * t], q0);
  atomicAdd(&gsq[2 * t + 1], q1);
}

// ------------- BN apply (inline mu/rsqrt) + ReLU -> y (bf16) ----------------
__global__ void bn_apply(const ushort* __restrict__ agg, const float* __restrict__ gsum,
                         const float* __restrict__ gsq, const float* __restrict__ gamma,
                         const float* __restrict__ beta, ushort* __restrict__ y,
                         float invN, int total4) {
  const int i = blockIdx.x * blockDim.x + threadIdx.x;
  if (i >= total4) return;
  const int base = i << 2;
  const int c = base & (HC - 1);
  const float4 gs = *(const float4*)(gsum + c);
  const float4 gq = *(const float4*)(gsq + c);
  const float4 ga = *(const float4*)(gamma + c);
  const float4 be = *(const float4*)(beta + c);
  const ushort4 u = *(const ushort4*)(agg + base);
  float m, var;
  ushort4 o;
  m = gs.x * invN; var = gq.x * invN - m * m;
  o.x = f2bf(fmaxf(0.f, (bf2f(u.x) - m) * rsqrtf(var + 1e-5f) * ga.x + be.x));
  m = gs.y * invN; var = gq.y * invN - m * m;
  o.y = f2bf(fmaxf(0.f, (bf2f(u.y) - m) * rsqrtf(var + 1e-5f) * ga.y + be.y));
  m = gs.z * invN; var = gq.z * invN - m * m;
  o.z = f2bf(fmaxf(0.f, (bf2f(u.z) - m) * rsqrtf(var + 1e-5f) * ga.z + be.z));
  m = gs.w * invN; var = gq.w * invN - m * m;
  o.w = f2bf(fmaxf(0.f, (bf2f(u.w) - m) * rsqrtf(var + 1e-5f) * ga.w + be.w));
  *(ushort4*)(y + base) = o;
}

// ------------- source-grouped link scoring: 1 wave/source node --------------
// y[s] loaded once to regs; only y[t] gathered per edge (prefetch-4).
__global__ __launch_bounds__(256) void score_g(
    const ushort* __restrict__ y, const int* __restrict__ off2,
    const int* __restrict__ cnt2, const int* __restrict__ csr_t,
    const int* __restrict__ csr_eid, float* __restrict__ out, int Nn) {
  const int node = blockIdx.x * 4 + (threadIdx.x >> 6);
  const int lane = threadIdx.x & 63;
  if (node >= Nn) return;
  const int start = off2[node];
  const int deg   = cnt2[node];
  if (deg == 0) return;
  float a[8];
  {
    const u16x8 us = *(const u16x8*)(y + (size_t)node * HC + lane * 8);
    #pragma unroll
    for (int c = 0; c < 8; ++c) a[c] = bf2f((ushort)us[c]);
  }
  const int* pt = csr_t + start;
  const int* pe = csr_eid + start;
  auto row = [&](int idx) {
    return *(const u16x8*)(y + (size_t)pt[idx] * HC + lane * 8);
  };
  auto emit = [&](const u16x8 ut, int eid) {
    float s = 0.f;
    #pragma unroll
    for (int c = 0; c < 8; ++c) s += a[c] * bf2f((ushort)ut[c]);
    #pragma unroll
    for (int off = 32; off > 0; off >>= 1) s += __shfl_down(s, off, 64);
    if (lane == 0) out[eid] = s;
  };
  u16x8 b0 = {}, b1 = {}, b2 = {}, b3 = {};
  b0 = row(0);
  if (deg > 1) b1 = row(1);
  if (deg > 2) b2 = row(2);
  if (deg > 3) b3 = row(3);
  int j = 0;
  for (; j + 4 <= deg; j += 4) {
    const u16x8 c0 = b0; if (j + 4 < deg) b0 = row(j + 4);
    const u16x8 c1 = b1; if (j + 5 < deg) b1 = row(j + 5);
    const u16x8 c2 = b2; if (j + 6 < deg) b2 = row(j + 6);
    const u16x8 c3 = b3; if (j + 7 < deg) b3 = row(j + 7);
    emit(c0, pe[j]); emit(c1, pe[j + 1]); emit(c2, pe[j + 2]); emit(c3, pe[j + 3]);
  }
  const int r = deg - j;
  if (r > 0) emit(b0, pe[j]);
  if (r > 1) emit(b1, pe[j + 1]);
  if (r > 2) emit(b2, pe[j + 2]);
}

extern "C" void kernel_launch(void* const* d_in, const int* in_sizes, int n_in,
                              void* d_out, int out_size, void* d_ws, size_t ws_size,
                              hipStream_t stream) {
  const float* x     = (const float*)d_in[0];
  const int*   ei    = (const int*)d_in[1];
  const int*   eli   = (const int*)d_in[2];
  const float* W_l   = (const float*)d_in[3];
  const float* W_r   = (const float*)d_in[4];
  const float* att   = (const float*)d_in[5];
  // d_in[6] = bias: cancels exactly inside train-mode BatchNorm -> unused.
  const float* gamma = (const float*)d_in[7];
  const float* beta  = (const float*)d_in[8];
  float* out = (float*)d_out;

  const int Nn = in_sizes[0] / IN_CH;  // 20000
  const int E  = in_sizes[1] / 2;      // 320000
  const int EL = in_sizes[2] / 2;      // 100000

  // ---- workspace layout ----
  ushort* xlb = (ushort*)d_ws;                     // Nn*HC bf16 (reused as y)
  ushort* xrb = xlb + (size_t)Nn * HC;             // Nn*HC bf16 (reused as agg)
  ushort* xbf = xrb + (size_t)Nn * HC;             // Nn*IN_CH bf16
  ushort* btb = xbf + (size_t)Nn * IN_CH;          // NPACK*IN_CH bf16
  int* counts   = (int*)(btb + (size_t)NPACK * IN_CH);  // Nn ┐ single
  int* counts2  = counts + Nn;                          // Nn │ memset
  float* gsum   = (float*)(counts2 + Nn);               // HC │ region
  float* gsq    = gsum + HC;                            // HC ┘
  int* offsets  = (int*)(gsq + HC);     // Nn
  int* cursor   = offsets + Nn;         // Nn
  int* bsumsA   = cursor + Nn;          // 256
  int* offsets2 = bsumsA + 256;         // Nn
  int* cursor2  = offsets2 + Nn;        // Nn
  int* bsumsB   = cursor2 + Nn;         // 256
  int* csr_src  = bsumsB + 256;         // E
  int* csr_t    = csr_src + E;          // EL
  int* csr_eid  = csr_t + EL;           // EL
  ushort* agg = xrb;
  ushort* y   = xlb;  // xlb dead after gatv2_agg

  const int nb  = (Nn + 255) / 256;           // scan blocks per CSR (79)
  const int nbc = (Nn * IN_CH / 4 + 255) / 256;
  const int nbp = (NPACK * IN_CH + 255) / 256;
  const int nbh = (E + 255) / 256;
  const int nbh2 = (EL + 255) / 256;

  // 0) one memset: counts | counts2 | gsum | gsq
  hipMemsetAsync(counts, 0, (2 * (size_t)Nn + 2 * HC) * sizeof(int), stream);

  // 1) fused prep: cast + pack + both histograms
  prep<<<nbc + nbp + nbh + nbh2, 256, 0, stream>>>(
      x, xbf, W_l, W_r, btb, ei, counts, eli, counts2,
      Nn * IN_CH / 4, E, EL, nbc, nbp, nbh);

  // 2) one bf16 MFMA GEMM -> xlb | xrb
  dim3 ggrid(NPACK / 128, (Nn + 127) / 128);
  gemm_mfma<<<ggrid, 256, 0, stream>>>(xbf, btb, xlb, xrb, Nn);

  // 3) dual CSR (graph by dst, labels by src); scan2 folded into scan3
  scan1<<<2 * nb, 256, 0, stream>>>(counts, offsets, bsumsA,
                                    counts2, offsets2, bsumsB, Nn, nb);
  scan3<<<2 * nb, 256, 0, stream>>>(offsets, bsumsA, cursor,
                                    offsets2, bsumsB, cursor2, Nn, nb);
  csr_fill<<<nbh + nbh2, 256, 0, stream>>>(ei, cursor, csr_src,
                                           eli, cursor2, csr_t, csr_eid, E, EL, nbh);

  // 4) fused attention + softmax + aggregation (no atomics, 1 wave/node)
  gatv2_agg<<<(Nn + 3) / 4, 256, 0, stream>>>(xlb, xrb, att, offsets, counts,
                                              csr_src, agg, Nn);

  // 5) BatchNorm (train-mode batch stats) + ReLU -> bf16 y (bn_final inlined)
  bn_stats<<<200, 256, 0, stream>>>(agg, gsum, gsq, Nn);
  bn_apply<<<(Nn * HC / 4 + 255) / 256, 256, 0, stream>>>(
      agg, gsum, gsq, gamma, beta, y, 1.0f / (float)Nn, Nn * HC / 4);

  // 6) source-grouped link scoring
  score_g<<<(Nn + 3) / 4, 256, 0, stream>>>(y, offsets2, counts2, csr_t, csr_eid,
                                            out, Nn);
}

// Round 7
// 317.160 us; speedup vs baseline: 15.7837x; 1.0046x over previous
//
#include <hip/hip_runtime.h>
#include <hip/hip_bf16.h>
#include <cstdint>

#define IN_CH 512
#define HC    512   // HEADS*CH
#define HEADS 8
#define NPACK 1024  // W_l | W_r packed

typedef __attribute__((ext_vector_type(8))) short bf16x8;
typedef __attribute__((ext_vector_type(8))) ushort u16x8;
typedef __attribute__((ext_vector_type(4))) float f32x4;
typedef const __attribute__((address_space(1))) uint8_t* gaddr_t;
typedef __attribute__((address_space(3))) uint8_t* laddr_t;

__device__ inline ushort f2bf(float f) {  // round-to-nearest-even
  uint32_t u = __float_as_uint(f);
  return (ushort)((u + 0x7fffu + ((u >> 16) & 1u)) >> 16);
}
__device__ inline float bf2f(ushort u) {
  return __uint_as_float(((uint32_t)u) << 16);
}

// ---- fused prep: cast x->bf16 | pack W^T bf16 | hist(dst) | hist(label s) --
__global__ void prep(const float* __restrict__ x, ushort* __restrict__ xb,
                     const float* __restrict__ Wl, const float* __restrict__ Wr,
                     ushort* __restrict__ bt,
                     const int* __restrict__ ei, int* __restrict__ counts,
                     const int* __restrict__ eli, int* __restrict__ counts2,
                     int n4, int E, int EL, int nbc, int nbp, int nbh) {
  const int b = blockIdx.x;
  if (b < nbc) {
    const int i = b * 256 + threadIdx.x;
    if (i < n4) {
      const float4 v = ((const float4*)x)[i];
      ushort4 o;
      o.x = f2bf(v.x); o.y = f2bf(v.y); o.z = f2bf(v.z); o.w = f2bf(v.w);
      ((ushort4*)xb)[i] = o;
    }
  } else if (b < nbc + nbp) {
    const int i = (b - nbc) * 256 + threadIdx.x;
    if (i < NPACK * IN_CH) {
      const int n = i >> 9, k = i & 511;
      const float v = (n < HC) ? Wl[(size_t)k * HC + n] : Wr[(size_t)k * HC + (n - HC)];
      bt[i] = f2bf(v);
    }
  } else if (b < nbc + nbp + nbh) {
    const int e = (b - nbc - nbp) * 256 + threadIdx.x;
    if (e < E) atomicAdd(&counts[ei[E + e]], 1);
  } else {
    const int e = (b - nbc - nbp - nbh) * 256 + threadIdx.x;
    if (e < EL) atomicAdd(&counts2[eli[e]], 1);
  }
}

// ---- bf16 MFMA GEMM: [M,1024] = xb[M,512] @ Bt^T -> xlb | xrb (both bf16) --
__global__ __launch_bounds__(256) void gemm_mfma(
    const ushort* __restrict__ xb, const ushort* __restrict__ bt,
    ushort* __restrict__ xlb, ushort* __restrict__ xrb, int M) {
  __shared__ __align__(16) ushort As[128 * 32];  // [row][k], stride 32
  __shared__ __align__(16) ushort Bs[128 * 32];  // [col][k], stride 32
  const int wave = threadIdx.x >> 6, lane = threadIdx.x & 63;
  const int row0 = blockIdx.y * 128, col0 = blockIdx.x * 128;
  const int quad = lane >> 4, m16 = lane & 15;
  const int wrow = (wave >> 1) * 64, wcol = (wave & 1) * 64;
  const int srow = lane >> 2;
  const int scol = (lane & 3) * 8;
  const f32x4 zero = {0.f, 0.f, 0.f, 0.f};
  f32x4 acc[4][4];
  #pragma unroll
  for (int i = 0; i < 4; ++i)
    #pragma unroll
    for (int j = 0; j < 4; ++j) acc[i][j] = zero;

  for (int k0 = 0; k0 < IN_CH; k0 += 32) {
    #pragma unroll
    for (int c = 0; c < 2; ++c) {
      const int chunk = wave * 2 + c;
      const ushort* ga = xb + (size_t)(row0 + chunk * 16 + srow) * IN_CH + k0 + scol;
      __builtin_amdgcn_global_load_lds((gaddr_t)ga, (laddr_t)(As + chunk * 512), 16, 0, 0);
      const ushort* gb = bt + (size_t)(col0 + chunk * 16 + srow) * IN_CH + k0 + scol;
      __builtin_amdgcn_global_load_lds((gaddr_t)gb, (laddr_t)(Bs + chunk * 512), 16, 0, 0);
    }
    __syncthreads();
    bf16x8 af[4], bfr[4];
    #pragma unroll
    for (int i = 0; i < 4; ++i)
      af[i] = *(const bf16x8*)(As + (wrow + i * 16 + m16) * 32 + quad * 8);
    #pragma unroll
    for (int j = 0; j < 4; ++j)
      bfr[j] = *(const bf16x8*)(Bs + (wcol + j * 16 + m16) * 32 + quad * 8);
    #pragma unroll
    for (int i = 0; i < 4; ++i)
      #pragma unroll
      for (int j = 0; j < 4; ++j)
        acc[i][j] = __builtin_amdgcn_mfma_f32_16x16x32_bf16(af[i], bfr[j], acc[i][j], 0, 0, 0);
    __syncthreads();
  }
  const bool isL = (col0 < HC);
  ushort* dst = isL ? xlb : xrb;
  const int cbase = isL ? col0 : (col0 - HC);
  #pragma unroll
  for (int i = 0; i < 4; ++i) {
    const int r = row0 + wrow + i * 16 + quad * 4;
    #pragma unroll
    for (int j = 0; j < 4; ++j) {
      const int cg = cbase + wcol + j * 16 + m16;
      #pragma unroll
      for (int t = 0; t < 4; ++t) {
        const int rr = r + t;
        if (rr < M) dst[(size_t)rr * HC + cg] = f2bf(acc[i][j][t]);
      }
    }
  }
}

// ---------------- dual-CSR scan chain (graph + label) -----------------------
__global__ void scan1(const int* __restrict__ cA, int* __restrict__ oA, int* __restrict__ bA,
                      const int* __restrict__ cB, int* __restrict__ oB, int* __restrict__ bB,
                      int Nn, int nb) {
  const int half = (blockIdx.x >= nb) ? 1 : 0;
  const int blk  = blockIdx.x - half * nb;
  const int* counts = half ? cB : cA;
  int* offsets = half ? oB : oA;
  int* bsums   = half ? bB : bA;
  __shared__ int tmp[256];
  const int t = threadIdx.x;
  const int i = blk * 256 + t;
  const int v = (i < Nn) ? counts[i] : 0;
  tmp[t] = v;
  __syncthreads();
  for (int d = 1; d < 256; d <<= 1) {
    int add = (t >= d) ? tmp[t - d] : 0;
    __syncthreads();
    tmp[t] += add;
    __syncthreads();
  }
  if (i < Nn) offsets[i] = tmp[t] - v;  // exclusive
  if (t == 255) bsums[blk] = tmp[255];
}

// scan3 with inline block-prefix (folds old scan2): wave 0 sums bsums[0..blk)
__global__ void scan3(int* __restrict__ oA, const int* __restrict__ bA, int* __restrict__ curA,
                      int* __restrict__ oB, const int* __restrict__ bB, int* __restrict__ curB,
                      int Nn, int nb) {
  const int half = (blockIdx.x >= nb) ? 1 : 0;
  const int blk  = blockIdx.x - half * nb;
  int* offsets = half ? oB : oA;
  const int* bsums = half ? bB : bA;
  int* cursor  = half ? curB : curA;
  __shared__ int pref;
  if (threadIdx.x < 64) {
    int s = 0;
    for (int b = threadIdx.x; b < blk; b += 64) s += bsums[b];
    #pragma unroll
    for (int off = 32; off > 0; off >>= 1) s += __shfl_down(s, off, 64);
    if (threadIdx.x == 0) pref = s;
  }
  __syncthreads();
  const int i = blk * 256 + threadIdx.x;
  if (i < Nn) {
    const int o = offsets[i] + pref;
    offsets[i] = o;
    cursor[i] = o;
  }
}

__global__ void csr_fill(const int* __restrict__ ei, int* __restrict__ cursor,
                         int* __restrict__ csr_src,
                         const int* __restrict__ eli, int* __restrict__ cursor2,
                         int* __restrict__ csr_t, int* __restrict__ csr_eid,
                         int E, int EL, int nbE) {
  const int b = blockIdx.x;
  if (b < nbE) {
    const int e = b * 256 + threadIdx.x;
    if (e < E) {
      const int pos = atomicAdd(&cursor[ei[E + e]], 1);
      csr_src[pos] = ei[e];
    }
  } else {
    const int e = (b - nbE) * 256 + threadIdx.x;
    if (e < EL) {
      const int pos = atomicAdd(&cursor2[eli[e]], 1);
      csr_t[pos] = eli[EL + e];
      csr_eid[pos] = e;
    }
  }
}

// ------- fused GATv2: logits + softmax + aggregation, 2 waves/node ----------
// Each wave owns half the channels (4 heads); head groups are 16 lanes, so
// per-head softmax reduction stays in-wave (shfl_xor widths 1,2,4,8 @ 16).
// bf16 gathers 8 B/lane, fp32 accumulate, prefetch-depth-2.
// agg (bf16) may alias xrb: wave reads only xrb[node] half-row up front,
// writes only agg[node] half-row at the end -> row-local, safe.
__global__ __launch_bounds__(256) void gatv2_agg(
    const ushort* __restrict__ xlb, const ushort* xrb, const float* __restrict__ att,
    const int* __restrict__ offsets, const int* __restrict__ counts,
    const int* __restrict__ csr_src, ushort* agg, int Nn) {
  const int wid  = blockIdx.x * 4 + (threadIdx.x >> 6);
  const int node = wid >> 1;
  const int half = wid & 1;
  const int lane = threadIdx.x & 63;
  if (node >= Nn) return;
  const int cb = half * 256 + lane * 4;  // this wave's channel base for lane
  const int start = offsets[node];
  const int deg   = counts[node];
  float rv[4], tv[4];
  {
    const ushort4 ur = *(const ushort4*)(xrb + (size_t)node * HC + cb);
    rv[0] = bf2f(ur.x); rv[1] = bf2f(ur.y); rv[2] = bf2f(ur.z); rv[3] = bf2f(ur.w);
    const float4 t = *(const float4*)(att + cb);
    tv[0] = t.x; tv[1] = t.y; tv[2] = t.z; tv[3] = t.w;
  }
  float acc[4] = {};
  float densum = 0.f;
  const int* ps = csr_src + start;
  auto row = [&](int idx) {
    return *(const ushort4*)(xlb + (size_t)ps[idx] * HC + cb);
  };
  auto body = [&](const ushort4 cur) {
    float a[4];
    a[0] = bf2f(cur.x); a[1] = bf2f(cur.y); a[2] = bf2f(cur.z); a[3] = bf2f(cur.w);
    float s = 0.f;
    #pragma unroll
    for (int c = 0; c < 4; ++c) {
      const float v = a[c] + rv[c];
      s += fmaxf(v, 0.2f * v) * tv[c];  // leaky_relu(v,0.2) == max(v,0.2v)
    }
    // per-head (64-channel = 16-lane) reduction
    s += __shfl_xor(s, 1, 16);
    s += __shfl_xor(s, 2, 16);
    s += __shfl_xor(s, 4, 16);
    s += __shfl_xor(s, 8, 16);
    const float ea = __expf(s);
    densum += ea;
    #pragma unroll
    for (int c = 0; c < 4; ++c) acc[c] += ea * a[c];
  };

  ushort4 b0 = {0, 0, 0, 0}, b1 = {0, 0, 0, 0};
  if (deg > 0) b0 = row(0);
  if (deg > 1) b1 = row(1);
  int i = 0;
  for (; i + 2 <= deg; i += 2) {
    const ushort4 c0 = b0;
    if (i + 2 < deg) b0 = row(i + 2);
    const ushort4 c1 = b1;
    if (i + 3 < deg) b1 = row(i + 3);
    body(c0);
    body(c1);
  }
  if (i < deg) body(b0);

  const float inv = 1.0f / (densum + 1e-16f);
  ushort4 o;
  o.x = f2bf(acc[0] * inv); o.y = f2bf(acc[1] * inv);
  o.z = f2bf(acc[2] * inv); o.w = f2bf(acc[3] * inv);
  *(ushort4*)(agg + (size_t)node * HC + cb) = o;
}

// ------------- BatchNorm stats: per-channel sum / sumsq (bf16 agg) ----------
__global__ void bn_stats(const ushort* __restrict__ agg, float* __restrict__ gsum,
                         float* __restrict__ gsq, int Nn) {
  const int t = threadIdx.x;  // 256; thread covers channels 2t, 2t+1
  const int rows_per_block = (Nn + gridDim.x - 1) / gridDim.x;
  const int r0 = blockIdx.x * rows_per_block;
  const int r1 = min(Nn, r0 + rows_per_block);
  float s0 = 0.f, s1 = 0.f, q0 = 0.f, q1 = 0.f;
  for (int r = r0; r < r1; ++r) {
    const ushort2 u = ((const ushort2*)(agg + (size_t)r * HC))[t];
    const float v0 = bf2f(u.x), v1 = bf2f(u.y);
    s0 += v0; q0 += v0 * v0;
    s1 += v1; q1 += v1 * v1;
  }
  atomicAdd(&gsum[2 * t], s0);
  atomicAdd(&gsum[2 * t + 1], s1);
  atomicAdd(&gsq[2 * t], q0);
  atomicAdd(&gsq[2 * t + 1], q1);
}

// ------------- BN apply (inline mu/rsqrt) + ReLU -> y (bf16) ----------------
__global__ void bn_apply(const ushort* __restrict__ agg, const float* __restrict__ gsum,
                         const float* __restrict__ gsq, const float* __restrict__ gamma,
                         const float* __restrict__ beta, ushort* __restrict__ y,
                         float invN, int total4) {
  const int i = blockIdx.x * blockDim.x + threadIdx.x;
  if (i >= total4) return;
  const int base = i << 2;
  const int c = base & (HC - 1);
  const float4 gs = *(const float4*)(gsum + c);
  const float4 gq = *(const float4*)(gsq + c);
  const float4 ga = *(const float4*)(gamma + c);
  const float4 be = *(const float4*)(beta + c);
  const ushort4 u = *(const ushort4*)(agg + base);
  float m, var;
  ushort4 o;
  m = gs.x * invN; var = gq.x * invN - m * m;
  o.x = f2bf(fmaxf(0.f, (bf2f(u.x) - m) * rsqrtf(var + 1e-5f) * ga.x + be.x));
  m = gs.y * invN; var = gq.y * invN - m * m;
  o.y = f2bf(fmaxf(0.f, (bf2f(u.y) - m) * rsqrtf(var + 1e-5f) * ga.y + be.y));
  m = gs.z * invN; var = gq.z * invN - m * m;
  o.z = f2bf(fmaxf(0.f, (bf2f(u.z) - m) * rsqrtf(var + 1e-5f) * ga.z + be.z));
  m = gs.w * invN; var = gq.w * invN - m * m;
  o.w = f2bf(fmaxf(0.f, (bf2f(u.w) - m) * rsqrtf(var + 1e-5f) * ga.w + be.w));
  *(ushort4*)(y + base) = o;
}

// ------------- source-grouped link scoring: 1 wave/source node --------------
// y[s] loaded once to regs; only y[t] gathered per edge (prefetch-2).
__global__ __launch_bounds__(256) void score_g(
    const ushort* __restrict__ y, const int* __restrict__ off2,
    const int* __restrict__ cnt2, const int* __restrict__ csr_t,
    const int* __restrict__ csr_eid, float* __restrict__ out, int Nn) {
  const int node = blockIdx.x * 4 + (threadIdx.x >> 6);
  const int lane = threadIdx.x & 63;
  if (node >= Nn) return;
  const int start = off2[node];
  const int deg   = cnt2[node];
  if (deg == 0) return;
  float a[8];
  {
    const u16x8 us = *(const u16x8*)(y + (size_t)node * HC + lane * 8);
    #pragma unroll
    for (int c = 0; c < 8; ++c) a[c] = bf2f((ushort)us[c]);
  }
  const int* pt = csr_t + start;
  const int* pe = csr_eid + start;
  auto row = [&](int idx) {
    return *(const u16x8*)(y + (size_t)pt[idx] * HC + lane * 8);
  };
  auto emit = [&](const u16x8 ut, int eid) {
    float s = 0.f;
    #pragma unroll
    for (int c = 0; c < 8; ++c) s += a[c] * bf2f((ushort)ut[c]);
    #pragma unroll
    for (int off = 32; off > 0; off >>= 1) s += __shfl_down(s, off, 64);
    if (lane == 0) out[eid] = s;
  };
  u16x8 b0 = {}, b1 = {};
  b0 = row(0);
  if (deg > 1) b1 = row(1);
  int j = 0;
  for (; j + 2 <= deg; j += 2) {
    const u16x8 c0 = b0;
    if (j + 2 < deg) b0 = row(j + 2);
    const u16x8 c1 = b1;
    if (j + 3 < deg) b1 = row(j + 3);
    emit(c0, pe[j]);
    emit(c1, pe[j + 1]);
  }
  if (j < deg) emit(b0, pe[j]);
}

extern "C" void kernel_launch(void* const* d_in, const int* in_sizes, int n_in,
                              void* d_out, int out_size, void* d_ws, size_t ws_size,
                              hipStream_t stream) {
  const float* x     = (const float*)d_in[0];
  const int*   ei    = (const int*)d_in[1];
  const int*   eli   = (const int*)d_in[2];
  const float* W_l   = (const float*)d_in[3];
  const float* W_r   = (const float*)d_in[4];
  const float* att   = (const float*)d_in[5];
  // d_in[6] = bias: cancels exactly inside train-mode BatchNorm -> unused.
  const float* gamma = (const float*)d_in[7];
  const float* beta  = (const float*)d_in[8];
  float* out = (float*)d_out;

  const int Nn = in_sizes[0] / IN_CH;  // 20000
  const int E  = in_sizes[1] / 2;      // 320000
  const int EL = in_sizes[2] / 2;      // 100000

  // ---- workspace layout ----
  ushort* xlb = (ushort*)d_ws;                     // Nn*HC bf16 (reused as y)
  ushort* xrb = xlb + (size_t)Nn * HC;             // Nn*HC bf16 (reused as agg)
  ushort* xbf = xrb + (size_t)Nn * HC;             // Nn*IN_CH bf16
  ushort* btb = xbf + (size_t)Nn * IN_CH;          // NPACK*IN_CH bf16
  int* counts   = (int*)(btb + (size_t)NPACK * IN_CH);  // Nn ┐ single
  int* counts2  = counts + Nn;                          // Nn │ memset
  float* gsum   = (float*)(counts2 + Nn);               // HC │ region
  float* gsq    = gsum + HC;                            // HC ┘
  int* offsets  = (int*)(gsq + HC);     // Nn
  int* cursor   = offsets + Nn;         // Nn
  int* bsumsA   = cursor + Nn;          // 256
  int* offsets2 = bsumsA + 256;         // Nn
  int* cursor2  = offsets2 + Nn;        // Nn
  int* bsumsB   = cursor2 + Nn;         // 256
  int* csr_src  = bsumsB + 256;         // E
  int* csr_t    = csr_src + E;          // EL
  int* csr_eid  = csr_t + EL;           // EL
  ushort* agg = xrb;
  ushort* y   = xlb;  // xlb dead after gatv2_agg

  const int nb  = (Nn + 255) / 256;           // scan blocks per CSR (79)
  const int nbc = (Nn * IN_CH / 4 + 255) / 256;
  const int nbp = (NPACK * IN_CH + 255) / 256;
  const int nbh = (E + 255) / 256;
  const int nbh2 = (EL + 255) / 256;

  // 0) one memset: counts | counts2 | gsum | gsq
  hipMemsetAsync(counts, 0, (2 * (size_t)Nn + 2 * HC) * sizeof(int), stream);

  // 1) fused prep: cast + pack + both histograms
  prep<<<nbc + nbp + nbh + nbh2, 256, 0, stream>>>(
      x, xbf, W_l, W_r, btb, ei, counts, eli, counts2,
      Nn * IN_CH / 4, E, EL, nbc, nbp, nbh);

  // 2) one bf16 MFMA GEMM -> xlb | xrb
  dim3 ggrid(NPACK / 128, (Nn + 127) / 128);
  gemm_mfma<<<ggrid, 256, 0, stream>>>(xbf, btb, xlb, xrb, Nn);

  // 3) dual CSR (graph by dst, labels by src); scan2 folded into scan3
  scan1<<<2 * nb, 256, 0, stream>>>(counts, offsets, bsumsA,
                                    counts2, offsets2, bsumsB, Nn, nb);
  scan3<<<2 * nb, 256, 0, stream>>>(offsets, bsumsA, cursor,
                                    offsets2, bsumsB, cursor2, Nn, nb);
  csr_fill<<<nbh + nbh2, 256, 0, stream>>>(ei, cursor, csr_src,
                                           eli, cursor2, csr_t, csr_eid, E, EL, nbh);

  // 4) fused attention + softmax + aggregation (2 waves/node, no atomics)
  gatv2_agg<<<(2 * Nn + 3) / 4, 256, 0, stream>>>(xlb, xrb, att, offsets, counts,
                                                  csr_src, agg, Nn);

  // 5) BatchNorm (train-mode batch stats) + ReLU -> bf16 y (bn_final inlined)
  bn_stats<<<200, 256, 0, stream>>>(agg, gsum, gsq, Nn);
  bn_apply<<<(Nn * HC / 4 + 255) / 256, 256, 0, stream>>>(
      agg, gsum, gsq, gamma, beta, y, 1.0f / (float)Nn, Nn * HC / 4);

  // 6) source-grouped link scoring
  score_g<<<(Nn + 3) / 4, 256, 0, stream>>>(y, offsets2, counts2, csr_t, csr_eid,
                                            out, Nn);
}

// Round 8
// 303.284 us; speedup vs baseline: 16.5059x; 1.0458x over previous
//
#include <hip/hip_runtime.h>
#include <hip/hip_bf16.h>
#include <cstdint>

#define IN_CH 512
#define HC    512   // HEADS*CH
#define HEADS 8
#define NPACK 1024  // W_l | W_r packed

typedef __attribute__((ext_vector_type(8))) short bf16x8;
typedef __attribute__((ext_vector_type(8))) ushort u16x8;
typedef __attribute__((ext_vector_type(4))) float f32x4;
typedef const __attribute__((address_space(1))) uint8_t* gaddr_t;
typedef __attribute__((address_space(3))) uint8_t* laddr_t;

__device__ inline ushort f2bf(float f) {  // round-to-nearest-even
  uint32_t u = __float_as_uint(f);
  return (ushort)((u + 0x7fffu + ((u >> 16) & 1u)) >> 16);
}
__device__ inline float bf2f(ushort u) {
  return __uint_as_float(((uint32_t)u) << 16);
}

// ---- fused prep: cast x->bf16 | pack W^T bf16 | hist(dst) | hist(label s) --
__global__ void prep(const float* __restrict__ x, ushort* __restrict__ xb,
                     const float* __restrict__ Wl, const float* __restrict__ Wr,
                     ushort* __restrict__ bt,
                     const int* __restrict__ ei, int* __restrict__ counts,
                     const int* __restrict__ eli, int* __restrict__ counts2,
                     int n4, int E, int EL, int nbc, int nbp, int nbh) {
  const int b = blockIdx.x;
  if (b < nbc) {
    const int i = b * 256 + threadIdx.x;
    if (i < n4) {
      const float4 v = ((const float4*)x)[i];
      ushort4 o;
      o.x = f2bf(v.x); o.y = f2bf(v.y); o.z = f2bf(v.z); o.w = f2bf(v.w);
      ((ushort4*)xb)[i] = o;
    }
  } else if (b < nbc + nbp) {
    const int i = (b - nbc) * 256 + threadIdx.x;
    if (i < NPACK * IN_CH) {
      const int n = i >> 9, k = i & 511;
      const float v = (n < HC) ? Wl[(size_t)k * HC + n] : Wr[(size_t)k * HC + (n - HC)];
      bt[i] = f2bf(v);
    }
  } else if (b < nbc + nbp + nbh) {
    const int e = (b - nbc - nbp) * 256 + threadIdx.x;
    if (e < E) atomicAdd(&counts[ei[E + e]], 1);
  } else {
    const int e = (b - nbc - nbp - nbh) * 256 + threadIdx.x;
    if (e < EL) atomicAdd(&counts2[eli[e]], 1);
  }
}

// ---- bf16 MFMA GEMM: [M,1024] = xb[M,512] @ Bt^T -> xlb | xrb (both bf16) --
__global__ __launch_bounds__(256) void gemm_mfma(
    const ushort* __restrict__ xb, const ushort* __restrict__ bt,
    ushort* __restrict__ xlb, ushort* __restrict__ xrb, int M) {
  __shared__ __align__(16) ushort As[128 * 32];  // [row][k], stride 32
  __shared__ __align__(16) ushort Bs[128 * 32];  // [col][k], stride 32
  const int wave = threadIdx.x >> 6, lane = threadIdx.x & 63;
  const int row0 = blockIdx.y * 128, col0 = blockIdx.x * 128;
  const int quad = lane >> 4, m16 = lane & 15;
  const int wrow = (wave >> 1) * 64, wcol = (wave & 1) * 64;
  const int srow = lane >> 2;
  const int scol = (lane & 3) * 8;
  const f32x4 zero = {0.f, 0.f, 0.f, 0.f};
  f32x4 acc[4][4];
  #pragma unroll
  for (int i = 0; i < 4; ++i)
    #pragma unroll
    for (int j = 0; j < 4; ++j) acc[i][j] = zero;

  for (int k0 = 0; k0 < IN_CH; k0 += 32) {
    #pragma unroll
    for (int c = 0; c < 2; ++c) {
      const int chunk = wave * 2 + c;
      const ushort* ga = xb + (size_t)(row0 + chunk * 16 + srow) * IN_CH + k0 + scol;
      __builtin_amdgcn_global_load_lds((gaddr_t)ga, (laddr_t)(As + chunk * 512), 16, 0, 0);
      const ushort* gb = bt + (size_t)(col0 + chunk * 16 + srow) * IN_CH + k0 + scol;
      __builtin_amdgcn_global_load_lds((gaddr_t)gb, (laddr_t)(Bs + chunk * 512), 16, 0, 0);
    }
    __syncthreads();
    bf16x8 af[4], bfr[4];
    #pragma unroll
    for (int i = 0; i < 4; ++i)
      af[i] = *(const bf16x8*)(As + (wrow + i * 16 + m16) * 32 + quad * 8);
    #pragma unroll
    for (int j = 0; j < 4; ++j)
      bfr[j] = *(const bf16x8*)(Bs + (wcol + j * 16 + m16) * 32 + quad * 8);
    #pragma unroll
    for (int i = 0; i < 4; ++i)
      #pragma unroll
      for (int j = 0; j < 4; ++j)
        acc[i][j] = __builtin_amdgcn_mfma_f32_16x16x32_bf16(af[i], bfr[j], acc[i][j], 0, 0, 0);
    __syncthreads();
  }
  const bool isL = (col0 < HC);
  ushort* dst = isL ? xlb : xrb;
  const int cbase = isL ? col0 : (col0 - HC);
  #pragma unroll
  for (int i = 0; i < 4; ++i) {
    const int r = row0 + wrow + i * 16 + quad * 4;
    #pragma unroll
    for (int j = 0; j < 4; ++j) {
      const int cg = cbase + wcol + j * 16 + m16;
      #pragma unroll
      for (int t = 0; t < 4; ++t) {
        const int rr = r + t;
        if (rr < M) dst[(size_t)rr * HC + cg] = f2bf(acc[i][j][t]);
      }
    }
  }
}

// ---------------- dual-CSR scan chain (graph + label) -----------------------
__global__ void scan1(const int* __restrict__ cA, int* __restrict__ oA, int* __restrict__ bA,
                      const int* __restrict__ cB, int* __restrict__ oB, int* __restrict__ bB,
                      int Nn, int nb) {
  const int half = (blockIdx.x >= nb) ? 1 : 0;
  const int blk  = blockIdx.x - half * nb;
  const int* counts = half ? cB : cA;
  int* offsets = half ? oB : oA;
  int* bsums   = half ? bB : bA;
  __shared__ int tmp[256];
  const int t = threadIdx.x;
  const int i = blk * 256 + t;
  const int v = (i < Nn) ? counts[i] : 0;
  tmp[t] = v;
  __syncthreads();
  for (int d = 1; d < 256; d <<= 1) {
    int add = (t >= d) ? tmp[t - d] : 0;
    __syncthreads();
    tmp[t] += add;
    __syncthreads();
  }
  if (i < Nn) offsets[i] = tmp[t] - v;  // exclusive
  if (t == 255) bsums[blk] = tmp[255];
}

// scan3 with inline block-prefix (folds old scan2): wave 0 sums bsums[0..blk)
__global__ void scan3(int* __restrict__ oA, const int* __restrict__ bA, int* __restrict__ curA,
                      int* __restrict__ oB, const int* __restrict__ bB, int* __restrict__ curB,
                      int Nn, int nb) {
  const int half = (blockIdx.x >= nb) ? 1 : 0;
  const int blk  = blockIdx.x - half * nb;
  int* offsets = half ? oB : oA;
  const int* bsums = half ? bB : bA;
  int* cursor  = half ? curB : curA;
  __shared__ int pref;
  if (threadIdx.x < 64) {
    int s = 0;
    for (int b = threadIdx.x; b < blk; b += 64) s += bsums[b];
    #pragma unroll
    for (int off = 32; off > 0; off >>= 1) s += __shfl_down(s, off, 64);
    if (threadIdx.x == 0) pref = s;
  }
  __syncthreads();
  const int i = blk * 256 + threadIdx.x;
  if (i < Nn) {
    const int o = offsets[i] + pref;
    offsets[i] = o;
    cursor[i] = o;
  }
}

__global__ void csr_fill(const int* __restrict__ ei, int* __restrict__ cursor,
                         int* __restrict__ csr_src,
                         const int* __restrict__ eli, int* __restrict__ cursor2,
                         int* __restrict__ csr_t, int* __restrict__ csr_eid,
                         int E, int EL, int nbE) {
  const int b = blockIdx.x;
  if (b < nbE) {
    const int e = b * 256 + threadIdx.x;
    if (e < E) {
      const int pos = atomicAdd(&cursor[ei[E + e]], 1);
      csr_src[pos] = ei[e];
    }
  } else {
    const int e = (b - nbE) * 256 + threadIdx.x;
    if (e < EL) {
      const int pos = atomicAdd(&cursor2[eli[e]], 1);
      csr_t[pos] = eli[EL + e];
      csr_eid[pos] = e;
    }
  }
}

// ------- fused GATv2: logits + softmax + aggregation, 1 wave/node -----------
// Measured-best config (R5 structure): 16 B/lane bf16 gathers, prefetch-2,
// plus R6 byte-cuts (bf16 xr read, bf16 agg write). fp32 accumulate.
// agg (bf16) may alias xrb: wave reads only xrb[node] up front, writes only
// agg[node] at the end -> row-local, safe.
__global__ __launch_bounds__(256) void gatv2_agg(
    const ushort* __restrict__ xlb, const ushort* xrb, const float* __restrict__ att,
    const int* __restrict__ offsets, const int* __restrict__ counts,
    const int* __restrict__ csr_src, ushort* agg, int Nn) {
  const int node = blockIdx.x * 4 + (threadIdx.x >> 6);
  const int lane = threadIdx.x & 63;
  if (node >= Nn) return;
  const int start = offsets[node];
  const int deg   = counts[node];
  float rv[8], tv[8];
  {
    const u16x8 ur = *(const u16x8*)(xrb + (size_t)node * HC + lane * 8);
    #pragma unroll
    for (int c = 0; c < 8; ++c) rv[c] = bf2f((ushort)ur[c]);
    const float4* pa = (const float4*)(att + lane * 8);
    const float4 t0 = pa[0], t1 = pa[1];
    tv[0]=t0.x; tv[1]=t0.y; tv[2]=t0.z; tv[3]=t0.w;
    tv[4]=t1.x; tv[5]=t1.y; tv[6]=t1.z; tv[7]=t1.w;
  }
  float acc[8] = {};
  float densum = 0.f;
  const int* ps = csr_src + start;
  auto row = [&](int idx) {
    return *(const u16x8*)(xlb + (size_t)ps[idx] * HC + lane * 8);
  };
  auto body = [&](const u16x8 cur) {
    float a[8];
    #pragma unroll
    for (int c = 0; c < 8; ++c) a[c] = bf2f((ushort)cur[c]);
    float s = 0.f;
    #pragma unroll
    for (int c = 0; c < 8; ++c) {
      const float v = a[c] + rv[c];
      s += fmaxf(v, 0.2f * v) * tv[c];  // leaky_relu(v,0.2) == max(v,0.2v)
    }
    // per-head (64-channel = 8-lane) reduction
    s += __shfl_xor(s, 1, 8);
    s += __shfl_xor(s, 2, 8);
    s += __shfl_xor(s, 4, 8);
    const float ea = __expf(s);
    densum += ea;
    #pragma unroll
    for (int c = 0; c < 8; ++c) acc[c] += ea * a[c];
  };

  u16x8 b0 = {}, b1 = {};
  if (deg > 0) b0 = row(0);
  if (deg > 1) b1 = row(1);
  int i = 0;
  for (; i + 2 <= deg; i += 2) {
    const u16x8 c0 = b0;
    if (i + 2 < deg) b0 = row(i + 2);
    const u16x8 c1 = b1;
    if (i + 3 < deg) b1 = row(i + 3);
    body(c0);
    body(c1);
  }
  if (i < deg) body(b0);

  const float inv = 1.0f / (densum + 1e-16f);
  ushort* pd = agg + (size_t)node * HC + lane * 8;
  ushort4 o0, o1;
  o0.x = f2bf(acc[0] * inv); o0.y = f2bf(acc[1] * inv);
  o0.z = f2bf(acc[2] * inv); o0.w = f2bf(acc[3] * inv);
  o1.x = f2bf(acc[4] * inv); o1.y = f2bf(acc[5] * inv);
  o1.z = f2bf(acc[6] * inv); o1.w = f2bf(acc[7] * inv);
  *(ushort4*)(pd + 0) = o0;
  *(ushort4*)(pd + 4) = o1;
}

// ------------- BatchNorm stats: per-channel sum / sumsq (bf16 agg) ----------
__global__ void bn_stats(const ushort* __restrict__ agg, float* __restrict__ gsum,
                         float* __restrict__ gsq, int Nn) {
  const int t = threadIdx.x;  // 256; thread covers channels 2t, 2t+1
  const int rows_per_block = (Nn + gridDim.x - 1) / gridDim.x;
  const int r0 = blockIdx.x * rows_per_block;
  const int r1 = min(Nn, r0 + rows_per_block);
  float s0 = 0.f, s1 = 0.f, q0 = 0.f, q1 = 0.f;
  for (int r = r0; r < r1; ++r) {
    const ushort2 u = ((const ushort2*)(agg + (size_t)r * HC))[t];
    const float v0 = bf2f(u.x), v1 = bf2f(u.y);
    s0 += v0; q0 += v0 * v0;
    s1 += v1; q1 += v1 * v1;
  }
  atomicAdd(&gsum[2 * t], s0);
  atomicAdd(&gsum[2 * t + 1], s1);
  atomicAdd(&gsq[2 * t], q0);
  atomicAdd(&gsq[2 * t + 1], q1);
}

// ------------- BN apply (inline mu/rsqrt) + ReLU -> y (bf16) ----------------
__global__ void bn_apply(const ushort* __restrict__ agg, const float* __restrict__ gsum,
                         const float* __restrict__ gsq, const float* __restrict__ gamma,
                         const float* __restrict__ beta, ushort* __restrict__ y,
                         float invN, int total4) {
  const int i = blockIdx.x * blockDim.x + threadIdx.x;
  if (i >= total4) return;
  const int base = i << 2;
  const int c = base & (HC - 1);
  const float4 gs = *(const float4*)(gsum + c);
  const float4 gq = *(const float4*)(gsq + c);
  const float4 ga = *(const float4*)(gamma + c);
  const float4 be = *(const float4*)(beta + c);
  const ushort4 u = *(const ushort4*)(agg + base);
  float m, var;
  ushort4 o;
  m = gs.x * invN; var = gq.x * invN - m * m;
  o.x = f2bf(fmaxf(0.f, (bf2f(u.x) - m) * rsqrtf(var + 1e-5f) * ga.x + be.x));
  m = gs.y * invN; var = gq.y * invN - m * m;
  o.y = f2bf(fmaxf(0.f, (bf2f(u.y) - m) * rsqrtf(var + 1e-5f) * ga.y + be.y));
  m = gs.z * invN; var = gq.z * invN - m * m;
  o.z = f2bf(fmaxf(0.f, (bf2f(u.z) - m) * rsqrtf(var + 1e-5f) * ga.z + be.z));
  m = gs.w * invN; var = gq.w * invN - m * m;
  o.w = f2bf(fmaxf(0.f, (bf2f(u.w) - m) * rsqrtf(var + 1e-5f) * ga.w + be.w));
  *(ushort4*)(y + base) = o;
}

// ------------- source-grouped link scoring: 1 wave/source node --------------
// y[s] loaded once to regs; only y[t] gathered per edge (prefetch-2).
__global__ __launch_bounds__(256) void score_g(
    const ushort* __restrict__ y, const int* __restrict__ off2,
    const int* __restrict__ cnt2, const int* __restrict__ csr_t,
    const int* __restrict__ csr_eid, float* __restrict__ out, int Nn) {
  const int node = blockIdx.x * 4 + (threadIdx.x >> 6);
  const int lane = threadIdx.x & 63;
  if (node >= Nn) return;
  const int start = off2[node];
  const int deg   = cnt2[node];
  if (deg == 0) return;
  float a[8];
  {
    const u16x8 us = *(const u16x8*)(y + (size_t)node * HC + lane * 8);
    #pragma unroll
    for (int c = 0; c < 8; ++c) a[c] = bf2f((ushort)us[c]);
  }
  const int* pt = csr_t + start;
  const int* pe = csr_eid + start;
  auto row = [&](int idx) {
    return *(const u16x8*)(y + (size_t)pt[idx] * HC + lane * 8);
  };
  auto emit = [&](const u16x8 ut, int eid) {
    float s = 0.f;
    #pragma unroll
    for (int c = 0; c < 8; ++c) s += a[c] * bf2f((ushort)ut[c]);
    #pragma unroll
    for (int off = 32; off > 0; off >>= 1) s += __shfl_down(s, off, 64);
    if (lane == 0) out[eid] = s;
  };
  u16x8 b0 = {}, b1 = {};
  b0 = row(0);
  if (deg > 1) b1 = row(1);
  int j = 0;
  for (; j + 2 <= deg; j += 2) {
    const u16x8 c0 = b0;
    if (j + 2 < deg) b0 = row(j + 2);
    const u16x8 c1 = b1;
    if (j + 3 < deg) b1 = row(j + 3);
    emit(c0, pe[j]);
    emit(c1, pe[j + 1]);
  }
  if (j < deg) emit(b0, pe[j]);
}

extern "C" void kernel_launch(void* const* d_in, const int* in_sizes, int n_in,
                              void* d_out, int out_size, void* d_ws, size_t ws_size,
                              hipStream_t stream) {
  const float* x     = (const float*)d_in[0];
  const int*   ei    = (const int*)d_in[1];
  const int*   eli   = (const int*)d_in[2];
  const float* W_l   = (const float*)d_in[3];
  const float* W_r   = (const float*)d_in[4];
  const float* att   = (const float*)d_in[5];
  // d_in[6] = bias: cancels exactly inside train-mode BatchNorm -> unused.
  const float* gamma = (const float*)d_in[7];
  const float* beta  = (const float*)d_in[8];
  float* out = (float*)d_out;

  const int Nn = in_sizes[0] / IN_CH;  // 20000
  const int E  = in_sizes[1] / 2;      // 320000
  const int EL = in_sizes[2] / 2;      // 100000

  // ---- workspace layout ----
  ushort* xlb = (ushort*)d_ws;                     // Nn*HC bf16 (reused as y)
  ushort* xrb = xlb + (size_t)Nn * HC;             // Nn*HC bf16 (reused as agg)
  ushort* xbf = xrb + (size_t)Nn * HC;             // Nn*IN_CH bf16
  ushort* btb = xbf + (size_t)Nn * IN_CH;          // NPACK*IN_CH bf16
  int* counts   = (int*)(btb + (size_t)NPACK * IN_CH);  // Nn ┐ single
  int* counts2  = counts + Nn;                          // Nn │ memset
  float* gsum   = (float*)(counts2 + Nn);               // HC │ region
  float* gsq    = gsum + HC;                            // HC ┘
  int* offsets  = (int*)(gsq + HC);     // Nn
  int* cursor   = offsets + Nn;         // Nn
  int* bsumsA   = cursor + Nn;          // 256
  int* offsets2 = bsumsA + 256;         // Nn
  int* cursor2  = offsets2 + Nn;        // Nn
  int* bsumsB   = cursor2 + Nn;         // 256
  int* csr_src  = bsumsB + 256;         // E
  int* csr_t    = csr_src + E;          // EL
  int* csr_eid  = csr_t + EL;           // EL
  ushort* agg = xrb;
  ushort* y   = xlb;  // xlb dead after gatv2_agg

  const int nb  = (Nn + 255) / 256;           // scan blocks per CSR (79)
  const int nbc = (Nn * IN_CH / 4 + 255) / 256;
  const int nbp = (NPACK * IN_CH + 255) / 256;
  const int nbh = (E + 255) / 256;
  const int nbh2 = (EL + 255) / 256;

  // 0) one memset: counts | counts2 | gsum | gsq
  hipMemsetAsync(counts, 0, (2 * (size_t)Nn + 2 * HC) * sizeof(int), stream);

  // 1) fused prep: cast + pack + both histograms
  prep<<<nbc + nbp + nbh + nbh2, 256, 0, stream>>>(
      x, xbf, W_l, W_r, btb, ei, counts, eli, counts2,
      Nn * IN_CH / 4, E, EL, nbc, nbp, nbh);

  // 2) one bf16 MFMA GEMM -> xlb | xrb
  dim3 ggrid(NPACK / 128, (Nn + 127) / 128);
  gemm_mfma<<<ggrid, 256, 0, stream>>>(xbf, btb, xlb, xrb, Nn);

  // 3) dual CSR (graph by dst, labels by src); scan2 folded into scan3
  scan1<<<2 * nb, 256, 0, stream>>>(counts, offsets, bsumsA,
                                    counts2, offsets2, bsumsB, Nn, nb);
  scan3<<<2 * nb, 256, 0, stream>>>(offsets, bsumsA, cursor,
                                    offsets2, bsumsB, cursor2, Nn, nb);
  csr_fill<<<nbh + nbh2, 256, 0, stream>>>(ei, cursor, csr_src,
                                           eli, cursor2, csr_t, csr_eid, E, EL, nbh);

  // 4) fused attention + softmax + aggregation (1 wave/node, no atomics)
  gatv2_agg<<<(Nn + 3) / 4, 256, 0, stream>>>(xlb, xrb, att, offsets, counts,
                                              csr_src, agg, Nn);

  // 5) BatchNorm (train-mode batch stats) + ReLU -> bf16 y (bn_final inlined)
  bn_stats<<<200, 256, 0, stream>>>(agg, gsum, gsq, Nn);
  bn_apply<<<(Nn * HC / 4 + 255) / 256, 256, 0, stream>>>(
      agg, gsum, gsq, gamma, beta, y, 1.0f / (float)Nn, Nn * HC / 4);

  // 6) source-grouped link scoring
  score_g<<<(Nn + 3) / 4, 256, 0, stream>>>(y, offsets2, counts2, csr_t, csr_eid,
                                            out, Nn);
}

// Round 10
// 297.270 us; speedup vs baseline: 16.8398x; 1.0202x over previous
//
#include <hip/hip_runtime.h>
#include <hip/hip_bf16.h>
#include <cstdint>

#define IN_CH 512
#define HC    512   // HEADS*CH
#define HEADS 8
#define NPACK 1024  // W_l | W_r packed

typedef __attribute__((ext_vector_type(8))) short bf16x8;
typedef __attribute__((ext_vector_type(8))) ushort u16x8;
typedef __attribute__((ext_vector_type(4))) float f32x4;
typedef const __attribute__((address_space(1))) uint8_t* gaddr_t;
typedef __attribute__((address_space(3))) uint8_t* laddr_t;

__device__ inline ushort f2bf(float f) {  // round-to-nearest-even
  uint32_t u = __float_as_uint(f);
  return (ushort)((u + 0x7fffu + ((u >> 16) & 1u)) >> 16);
}
__device__ inline float bf2f(ushort u) {
  return __uint_as_float(((uint32_t)u) << 16);
}

// ---- fused prep: cast x->bf16 | pack W^T bf16 | hist(dst) | hist(label s) --
__global__ void prep(const float* __restrict__ x, ushort* __restrict__ xb,
                     const float* __restrict__ Wl, const float* __restrict__ Wr,
                     ushort* __restrict__ bt,
                     const int* __restrict__ ei, int* __restrict__ counts,
                     const int* __restrict__ eli, int* __restrict__ counts2,
                     int n4, int E, int EL, int nbc, int nbp, int nbh) {
  const int b = blockIdx.x;
  if (b < nbc) {
    const int i = b * 256 + threadIdx.x;
    if (i < n4) {
      const float4 v = ((const float4*)x)[i];
      ushort4 o;
      o.x = f2bf(v.x); o.y = f2bf(v.y); o.z = f2bf(v.z); o.w = f2bf(v.w);
      ((ushort4*)xb)[i] = o;
    }
  } else if (b < nbc + nbp) {
    const int i = (b - nbc) * 256 + threadIdx.x;
    if (i < NPACK * IN_CH) {
      const int n = i >> 9, k = i & 511;
      const float v = (n < HC) ? Wl[(size_t)k * HC + n] : Wr[(size_t)k * HC + (n - HC)];
      bt[i] = f2bf(v);
    }
  } else if (b < nbc + nbp + nbh) {
    const int e = (b - nbc - nbp) * 256 + threadIdx.x;
    if (e < E) atomicAdd(&counts[ei[E + e]], 1);
  } else {
    const int e = (b - nbc - nbp - nbh) * 256 + threadIdx.x;
    if (e < EL) atomicAdd(&counts2[eli[e]], 1);
  }
}

// ---- bf16 MFMA GEMM: [M,1024] = xb[M,512] @ Bt^T -> xlb | xrb (both bf16) --
__global__ __launch_bounds__(256) void gemm_mfma(
    const ushort* __restrict__ xb, const ushort* __restrict__ bt,
    ushort* __restrict__ xlb, ushort* __restrict__ xrb, int M) {
  __shared__ __align__(16) ushort As[128 * 32];  // [row][k], stride 32
  __shared__ __align__(16) ushort Bs[128 * 32];  // [col][k], stride 32
  const int wave = threadIdx.x >> 6, lane = threadIdx.x & 63;
  const int row0 = blockIdx.y * 128, col0 = blockIdx.x * 128;
  const int quad = lane >> 4, m16 = lane & 15;
  const int wrow = (wave >> 1) * 64, wcol = (wave & 1) * 64;
  const int srow = lane >> 2;
  const int scol = (lane & 3) * 8;
  const f32x4 zero = {0.f, 0.f, 0.f, 0.f};
  f32x4 acc[4][4];
  #pragma unroll
  for (int i = 0; i < 4; ++i)
    #pragma unroll
    for (int j = 0; j < 4; ++j) acc[i][j] = zero;

  for (int k0 = 0; k0 < IN_CH; k0 += 32) {
    #pragma unroll
    for (int c = 0; c < 2; ++c) {
      const int chunk = wave * 2 + c;
      const ushort* ga = xb + (size_t)(row0 + chunk * 16 + srow) * IN_CH + k0 + scol;
      __builtin_amdgcn_global_load_lds((gaddr_t)ga, (laddr_t)(As + chunk * 512), 16, 0, 0);
      const ushort* gb = bt + (size_t)(col0 + chunk * 16 + srow) * IN_CH + k0 + scol;
      __builtin_amdgcn_global_load_lds((gaddr_t)gb, (laddr_t)(Bs + chunk * 512), 16, 0, 0);
    }
    __syncthreads();
    bf16x8 af[4], bfr[4];
    #pragma unroll
    for (int i = 0; i < 4; ++i)
      af[i] = *(const bf16x8*)(As + (wrow + i * 16 + m16) * 32 + quad * 8);
    #pragma unroll
    for (int j = 0; j < 4; ++j)
      bfr[j] = *(const bf16x8*)(Bs + (wcol + j * 16 + m16) * 32 + quad * 8);
    #pragma unroll
    for (int i = 0; i < 4; ++i)
      #pragma unroll
      for (int j = 0; j < 4; ++j)
        acc[i][j] = __builtin_amdgcn_mfma_f32_16x16x32_bf16(af[i], bfr[j], acc[i][j], 0, 0, 0);
    __syncthreads();
  }
  const bool isL = (col0 < HC);
  ushort* dst = isL ? xlb : xrb;
  const int cbase = isL ? col0 : (col0 - HC);
  #pragma unroll
  for (int i = 0; i < 4; ++i) {
    const int r = row0 + wrow + i * 16 + quad * 4;
    #pragma unroll
    for (int j = 0; j < 4; ++j) {
      const int cg = cbase + wcol + j * 16 + m16;
      #pragma unroll
      for (int t = 0; t < 4; ++t) {
        const int rr = r + t;
        if (rr < M) dst[(size_t)rr * HC + cg] = f2bf(acc[i][j][t]);
      }
    }
  }
}

// ---- fused dual-CSR exclusive scan (scan1+scan3 in one dispatch) -----------
// Each block scans its 256 counts, publishes its block total (val+1, 0=not
// ready) via device-scope atomicExch, then wave 0 spin-reads ALL predecessor
// aggregates (no serial chain; <=79 predecessors => 2 rounds of 64 lanes) and
// butterfly-reduces. All 2*nb blocks are co-resident (158 << capacity), and
// every block publishes before waiting -> no deadlock.
__global__ __launch_bounds__(256) void scan_fused(
    const int* __restrict__ cA, int* __restrict__ oA, int* __restrict__ curA,
    int* __restrict__ fA,
    const int* __restrict__ cB, int* __restrict__ oB, int* __restrict__ curB,
    int* __restrict__ fB, int Nn, int nb) {
  const int half = (blockIdx.x >= nb) ? 1 : 0;
  const int blk  = blockIdx.x - half * nb;
  const int* counts = half ? cB : cA;
  int* offsets = half ? oB : oA;
  int* cursor  = half ? curB : curA;
  int* flags   = half ? fB : fA;
  __shared__ int tmp[256];
  __shared__ int sPref;
  const int t = threadIdx.x;
  const int i = blk * 256 + t;
  const int v = (i < Nn) ? counts[i] : 0;
  tmp[t] = v;
  __syncthreads();
  for (int d = 1; d < 256; d <<= 1) {
    int add = (t >= d) ? tmp[t - d] : 0;
    __syncthreads();
    tmp[t] += add;
    __syncthreads();
  }
  if (t == 0) atomicExch(&flags[blk], tmp[255] + 1);  // publish aggregate
  if (t < 64) {
    int s = 0;
    for (int b = t; b < blk; b += 64) {
      int f;
      do { f = atomicOr(&flags[b], 0); } while (f == 0);
      s += f - 1;
    }
    #pragma unroll
    for (int off = 32; off > 0; off >>= 1) s += __shfl_down(s, off, 64);
    if (t == 0) sPref = s;
  }
  __syncthreads();
  const int pref = sPref;
  if (i < Nn) {
    const int o = tmp[t] - v + pref;  // exclusive prefix
    offsets[i] = o;
    cursor[i] = o;
  }
}

__global__ void csr_fill(const int* __restrict__ ei, int* __restrict__ cursor,
                         int* __restrict__ csr_src,
                         const int* __restrict__ eli, int* __restrict__ cursor2,
                         int* __restrict__ csr_t, int* __restrict__ csr_eid,
                         int E, int EL, int nbE) {
  const int b = blockIdx.x;
  if (b < nbE) {
    const int e = b * 256 + threadIdx.x;
    if (e < E) {
      const int pos = atomicAdd(&cursor[ei[E + e]], 1);
      csr_src[pos] = ei[e];
    }
  } else {
    const int e = (b - nbE) * 256 + threadIdx.x;
    if (e < EL) {
      const int pos = atomicAdd(&cursor2[eli[e]], 1);
      csr_t[pos] = eli[EL + e];
      csr_eid[pos] = e;
    }
  }
}

// ------- fused GATv2: logits + softmax + aggregation, 1 wave/node -----------
// Measured-best config (R8): 16 B/lane bf16 gathers, prefetch-2, bf16 xr/agg.
__global__ __launch_bounds__(256) void gatv2_agg(
    const ushort* __restrict__ xlb, const ushort* xrb, const float* __restrict__ att,
    const int* __restrict__ offsets, const int* __restrict__ counts,
    const int* __restrict__ csr_src, ushort* agg, int Nn) {
  const int node = blockIdx.x * 4 + (threadIdx.x >> 6);
  const int lane = threadIdx.x & 63;
  if (node >= Nn) return;
  const int start = offsets[node];
  const int deg   = counts[node];
  float rv[8], tv[8];
  {
    const u16x8 ur = *(const u16x8*)(xrb + (size_t)node * HC + lane * 8);
    #pragma unroll
    for (int c = 0; c < 8; ++c) rv[c] = bf2f((ushort)ur[c]);
    const float4* pa = (const float4*)(att + lane * 8);
    const float4 t0 = pa[0], t1 = pa[1];
    tv[0]=t0.x; tv[1]=t0.y; tv[2]=t0.z; tv[3]=t0.w;
    tv[4]=t1.x; tv[5]=t1.y; tv[6]=t1.z; tv[7]=t1.w;
  }
  float acc[8] = {};
  float densum = 0.f;
  const int* ps = csr_src + start;
  auto row = [&](int idx) {
    return *(const u16x8*)(xlb + (size_t)ps[idx] * HC + lane * 8);
  };
  auto body = [&](const u16x8 cur) {
    float a[8];
    #pragma unroll
    for (int c = 0; c < 8; ++c) a[c] = bf2f((ushort)cur[c]);
    float s = 0.f;
    #pragma unroll
    for (int c = 0; c < 8; ++c) {
      const float v = a[c] + rv[c];
      s += fmaxf(v, 0.2f * v) * tv[c];  // leaky_relu(v,0.2) == max(v,0.2v)
    }
    s += __shfl_xor(s, 1, 8);
    s += __shfl_xor(s, 2, 8);
    s += __shfl_xor(s, 4, 8);
    const float ea = __expf(s);
    densum += ea;
    #pragma unroll
    for (int c = 0; c < 8; ++c) acc[c] += ea * a[c];
  };

  u16x8 b0 = {}, b1 = {};
  if (deg > 0) b0 = row(0);
  if (deg > 1) b1 = row(1);
  int i = 0;
  for (; i + 2 <= deg; i += 2) {
    const u16x8 c0 = b0;
    if (i + 2 < deg) b0 = row(i + 2);
    const u16x8 c1 = b1;
    if (i + 3 < deg) b1 = row(i + 3);
    body(c0);
    body(c1);
  }
  if (i < deg) body(b0);

  const float inv = 1.0f / (densum + 1e-16f);
  ushort* pd = agg + (size_t)node * HC + lane * 8;
  ushort4 o0, o1;
  o0.x = f2bf(acc[0] * inv); o0.y = f2bf(acc[1] * inv);
  o0.z = f2bf(acc[2] * inv); o0.w = f2bf(acc[3] * inv);
  o1.x = f2bf(acc[4] * inv); o1.y = f2bf(acc[5] * inv);
  o1.z = f2bf(acc[6] * inv); o1.w = f2bf(acc[7] * inv);
  *(ushort4*)(pd + 0) = o0;
  *(ushort4*)(pd + 4) = o1;
}

// ------------- BatchNorm stats + last-block finalize ------------------------
// Per-channel sum/sumsq atomics; the LAST block (done-counter) computes the
// per-channel affine: aScale = rs*gamma, bShift = beta - mu*rs*gamma, so
// BN+ReLU becomes y = max(0, v*aScale + bShift), applied inline in score_g.
__global__ void bn_stats(const ushort* __restrict__ agg, float* __restrict__ gsum,
                         float* __restrict__ gsq, int* __restrict__ ctr,
                         const float* __restrict__ gamma, const float* __restrict__ beta,
                         float* __restrict__ aScale, float* __restrict__ bShift,
                         float invN, int Nn) {
  const int t = threadIdx.x;  // 256; thread covers channels 2t, 2t+1
  const int rows_per_block = (Nn + gridDim.x - 1) / gridDim.x;
  const int r0 = blockIdx.x * rows_per_block;
  const int r1 = min(Nn, r0 + rows_per_block);
  float s0 = 0.f, s1 = 0.f, q0 = 0.f, q1 = 0.f;
  for (int r = r0; r < r1; ++r) {
    const ushort2 u = ((const ushort2*)(agg + (size_t)r * HC))[t];
    const float v0 = bf2f(u.x), v1 = bf2f(u.y);
    s0 += v0; q0 += v0 * v0;
    s1 += v1; q1 += v1 * v1;
  }
  atomicAdd(&gsum[2 * t], s0);
  atomicAdd(&gsum[2 * t + 1], s1);
  atomicAdd(&gsq[2 * t], q0);
  atomicAdd(&gsq[2 * t + 1], q1);
  // ---- last-block finalize (syncthreads drains this block's atomics) ----
  __shared__ int isLast;
  __syncthreads();
  if (t == 0) {
    __threadfence();
    isLast = (atomicAdd(ctr, 1) == (int)gridDim.x - 1) ? 1 : 0;
  }
  __syncthreads();
  if (isLast) {
    #pragma unroll
    for (int k = 0; k < 2; ++k) {
      const int c = t + k * 256;
      const float sum = atomicAdd(&gsum[c], 0.0f);  // coherent read
      const float sq  = atomicAdd(&gsq[c], 0.0f);
      const float m = sum * invN;
      const float var = sq * invN - m * m;
      const float rs = rsqrtf(var + 1e-5f);
      const float a = rs * gamma[c];
      aScale[c] = a;
      bShift[c] = beta[c] - m * a;
    }
  }
}

// ------------- source-grouped link scoring with inline BN+ReLU --------------
// y never materialized: y[n,c] = max(0, agg[n,c]*aScale[c] + bShift[c]).
// y[s] computed once per node; per edge only agg[t] gathered (prefetch-2).
__global__ __launch_bounds__(256) void score_g(
    const ushort* __restrict__ agg, const float* __restrict__ aScale,
    const float* __restrict__ bShift, const int* __restrict__ off2,
    const int* __restrict__ cnt2, const int* __restrict__ csr_t,
    const int* __restrict__ csr_eid, float* __restrict__ out, int Nn) {
  const int node = blockIdx.x * 4 + (threadIdx.x >> 6);
  const int lane = threadIdx.x & 63;
  if (node >= Nn) return;
  const int start = off2[node];
  const int deg   = cnt2[node];
  if (deg == 0) return;
  float aS[8], bS[8], ys[8];
  {
    const float4* pa = (const float4*)(aScale + lane * 8);
    const float4 a0 = pa[0], a1 = pa[1];
    aS[0]=a0.x; aS[1]=a0.y; aS[2]=a0.z; aS[3]=a0.w;
    aS[4]=a1.x; aS[5]=a1.y; aS[6]=a1.z; aS[7]=a1.w;
    const float4* pb = (const float4*)(bShift + lane * 8);
    const float4 c0 = pb[0], c1 = pb[1];
    bS[0]=c0.x; bS[1]=c0.y; bS[2]=c0.z; bS[3]=c0.w;
    bS[4]=c1.x; bS[5]=c1.y; bS[6]=c1.z; bS[7]=c1.w;
    const u16x8 us = *(const u16x8*)(agg + (size_t)node * HC + lane * 8);
    #pragma unroll
    for (int c = 0; c < 8; ++c)
      ys[c] = fmaxf(0.f, bf2f((ushort)us[c]) * aS[c] + bS[c]);
  }
  const int* pt = csr_t + start;
  const int* pe = csr_eid + start;
  auto row = [&](int idx) {
    return *(const u16x8*)(agg + (size_t)pt[idx] * HC + lane * 8);
  };
  auto emit = [&](const u16x8 ut, int eid) {
    float s = 0.f;
    #pragma unroll
    for (int c = 0; c < 8; ++c)
      s += ys[c] * fmaxf(0.f, bf2f((ushort)ut[c]) * aS[c] + bS[c]);
    #pragma unroll
    for (int off = 32; off > 0; off >>= 1) s += __shfl_down(s, off, 64);
    if (lane == 0) out[eid] = s;
  };
  u16x8 b0 = {}, b1 = {};
  b0 = row(0);
  if (deg > 1) b1 = row(1);
  int j = 0;
  for (; j + 2 <= deg; j += 2) {
    const u16x8 c0 = b0;
    if (j + 2 < deg) b0 = row(j + 2);
    const u16x8 c1 = b1;
    if (j + 3 < deg) b1 = row(j + 3);
    emit(c0, pe[j]);
    emit(c1, pe[j + 1]);
  }
  if (j < deg) emit(b0, pe[j]);
}

extern "C" void kernel_launch(void* const* d_in, const int* in_sizes, int n_in,
                              void* d_out, int out_size, void* d_ws, size_t ws_size,
                              hipStream_t stream) {
  const float* x     = (const float*)d_in[0];
  const int*   ei    = (const int*)d_in[1];
  const int*   eli   = (const int*)d_in[2];
  const float* W_l   = (const float*)d_in[3];
  const float* W_r   = (const float*)d_in[4];
  const float* att   = (const float*)d_in[5];
  // d_in[6] = bias: cancels exactly inside train-mode BatchNorm -> unused.
  const float* gamma = (const float*)d_in[7];
  const float* beta  = (const float*)d_in[8];
  float* out = (float*)d_out;

  const int Nn = in_sizes[0] / IN_CH;  // 20000
  const int E  = in_sizes[1] / 2;      // 320000
  const int EL = in_sizes[2] / 2;      // 100000

  // ---- workspace layout ----
  ushort* xlb = (ushort*)d_ws;                     // Nn*HC bf16
  ushort* xrb = xlb + (size_t)Nn * HC;             // Nn*HC bf16 (reused as agg)
  ushort* xbf = xrb + (size_t)Nn * HC;             // Nn*IN_CH bf16
  ushort* btb = xbf + (size_t)Nn * IN_CH;          // NPACK*IN_CH bf16
  int* counts   = (int*)(btb + (size_t)NPACK * IN_CH);  // Nn ┐
  int* counts2  = counts + Nn;                          // Nn │ single
  float* gsum   = (float*)(counts2 + Nn);               // HC │ memset
  float* gsq    = gsum + HC;                            // HC │ region
  int* flagsA   = (int*)(gsq + HC);                     // 128│
  int* flagsB   = flagsA + 128;                         // 128│
  int* bnctr    = flagsB + 128;                         // 64 ┘ (padded)
  int* offsets  = bnctr + 64;           // Nn
  int* cursor   = offsets + Nn;         // Nn
  int* offsets2 = cursor + Nn;          // Nn
  int* cursor2  = offsets2 + Nn;        // Nn
  int* csr_src  = cursor2 + Nn;         // E
  int* csr_t    = csr_src + E;          // EL
  int* csr_eid  = csr_t + EL;           // EL
  float* aScale = (float*)(csr_eid + EL);  // HC
  float* bShift = aScale + HC;             // HC
  ushort* agg = xrb;

  const int nb  = (Nn + 255) / 256;           // scan blocks per CSR (79)
  const int nbc = (Nn * IN_CH / 4 + 255) / 256;
  const int nbp = (NPACK * IN_CH + 255) / 256;
  const int nbh = (E + 255) / 256;
  const int nbh2 = (EL + 255) / 256;

  // 0) one memset: counts | counts2 | gsum | gsq | flagsA | flagsB | bnctr
  (void)hipMemsetAsync(counts, 0, (2 * (size_t)Nn + 2 * HC + 320) * sizeof(int), stream);

  // 1) fused prep: cast + pack + both histograms
  prep<<<nbc + nbp + nbh + nbh2, 256, 0, stream>>>(
      x, xbf, W_l, W_r, btb, ei, counts, eli, counts2,
      Nn * IN_CH / 4, E, EL, nbc, nbp, nbh);

  // 2) one bf16 MFMA GEMM -> xlb | xrb
  dim3 ggrid(NPACK / 128, (Nn + 127) / 128);
  gemm_mfma<<<ggrid, 256, 0, stream>>>(xbf, btb, xlb, xrb, Nn);

  // 3) fused dual-CSR scan (lookback) + fill
  scan_fused<<<2 * nb, 256, 0, stream>>>(counts, offsets, cursor, flagsA,
                                         counts2, offsets2, cursor2, flagsB, Nn, nb);
  csr_fill<<<nbh + nbh2, 256, 0, stream>>>(ei, cursor, csr_src,
                                           eli, cursor2, csr_t, csr_eid, E, EL, nbh);

  // 4) fused attention + softmax + aggregation (1 wave/node, no atomics)
  gatv2_agg<<<(Nn + 3) / 4, 256, 0, stream>>>(xlb, xrb, att, offsets, counts,
                                              csr_src, agg, Nn);

  // 5) BN stats + last-block finalize -> aScale/bShift (no bn_apply pass)
  bn_stats<<<200, 256, 0, stream>>>(agg, gsum, gsq, bnctr, gamma, beta,
                                    aScale, bShift, 1.0f / (float)Nn, Nn);

  // 6) source-grouped link scoring with inline BN+ReLU
  score_g<<<(Nn + 3) / 4, 256, 0, stream>>>(agg, aScale, bShift, offsets2,
                                            counts2, csr_t, csr_eid, out, Nn);
}